// Round 12
// baseline (313.403 us; speedup 1.0000x reference)
//
#include <hip/hip_runtime.h>
#include <cstdint>
#include <cstddef>

typedef __bf16 bf16;
typedef __bf16 bf16x8 __attribute__((ext_vector_type(8)));
typedef __bf16 bf16x4 __attribute__((ext_vector_type(4)));
typedef float  f32x4  __attribute__((ext_vector_type(4)));

#define GLOAD_LDS16(g, l) __builtin_amdgcn_global_load_lds( \
    (const __attribute__((address_space(1))) unsigned int*)(g), \
    (__attribute__((address_space(3))) unsigned int*)(l), 16, 0, 0)

static constexpr int D_  = 1024;
static constexpr int H_  = 16;
static constexpr int HD_ = 64;
static constexpr int B_  = 8;
static constexpr int LQ_ = 512;
static constexpr int LK_ = 1024;
static constexpr int MQ_ = B_ * LQ_;   // 4096 query rows
static constexpr int MK_ = B_ * LK_;   // 8192 kv rows
static constexpr float LOG2E_ = 1.4426950408889634f;
static constexpr float INV_LN_LK_ = 0.14426950408889634f; // 1/ln(1024)
static constexpr float CSHIFT_ = 8.0f;                    // fixed softmax shift

// fast gelu (tanh form, folded to x*sigmoid(2z)); |err vs erf-gelu| <= ~1e-3
__device__ __forceinline__ float gelu_f(float v) {
    float v2 = v * v;
    float u = fmaf(0.035677408136f, v2, 0.7978845608028654f);
    float s = exp2f(v * u * -2.8853900817779268f);
    return v / (1.0f + s);
}

// ---------------------------------------------------------------- fused casts
__global__ __launch_bounds__(256)
void cast_all_k(const float* __restrict__ ipw, const float* __restrict__ outw,
                const float* __restrict__ w1,  const float* __restrict__ w2,
                const float* __restrict__ gw1, const float* __restrict__ q,
                const float* __restrict__ kv,
                bf16* __restrict__ ipw_b, bf16* __restrict__ outw_b,
                bf16* __restrict__ w1_b,  bf16* __restrict__ w2_b,
                bf16* __restrict__ gw1_b, bf16* __restrict__ x_b,
                bf16* __restrict__ kv_b) {
    const int b = blockIdx.x, t = threadIdx.x;
    const float* src; bf16* dst; long e;
    if (b < 1536)       { src = ipw;  dst = ipw_b;  e = (long)b * 2048; }
    else if (b < 2048)  { src = outw; dst = outw_b; e = (long)(b - 1536) * 2048; }
    else if (b < 4096)  { src = w1;   dst = w1_b;   e = (long)(b - 2048) * 2048; }
    else if (b < 6144)  { src = w2;   dst = w2_b;   e = (long)(b - 4096) * 2048; }
    else if (b < 7168)  { src = gw1;  dst = gw1_b;  e = (long)(b - 6144) * 2048; }
    else if (b < 11264) { src = kv;   dst = kv_b;   e = (long)(b - 7168) * 2048; }
    else {  // q: strided write into x_b left half (dld 2048)
        long e2 = (long)(b - 11264) * 2048 + t * 8;
        float4 a = *(const float4*)(q + e2);
        float4 c = *(const float4*)(q + e2 + 4);
        bf16x8 o;
        o[0]=(bf16)a.x; o[1]=(bf16)a.y; o[2]=(bf16)a.z; o[3]=(bf16)a.w;
        o[4]=(bf16)c.x; o[5]=(bf16)c.y; o[6]=(bf16)c.z; o[7]=(bf16)c.w;
        long row = e2 >> 10, col = e2 & 1023;
        *(bf16x8*)(x_b + row * 2048 + col) = o;
        return;
    }
    e += t * 8;
    float4 a = *(const float4*)(src + e);
    float4 c = *(const float4*)(src + e + 4);
    bf16x8 o;
    o[0]=(bf16)a.x; o[1]=(bf16)a.y; o[2]=(bf16)a.z; o[3]=(bf16)a.w;
    o[4]=(bf16)c.x; o[5]=(bf16)c.y; o[6]=(bf16)c.z; o[7]=(bf16)c.w;
    *(bf16x8*)(dst + e) = o;
}

// ---------------------------------------------------------------- 128x128 pipelined GEMM (gemmP)
template<int SPLITK>
__device__ __forceinline__
void gemmP_body(const bf16* __restrict__ A, int lda,
                const bf16* __restrict__ W, int ldw,
                const float* __restrict__ bias,
                bf16* __restrict__ Cb, int ldcb,
                float* __restrict__ Cf0, float* __restrict__ Cf1, int ldcf,
                int K, int aoff, int woff) {
    __shared__ __attribute__((aligned(16))) bf16 LDSp[3 * 8192];
    const int gx = gridDim.x, gy = gridDim.y;
    const int nwg = gx * gy * gridDim.z;
    const int flat = blockIdx.x + gx * (blockIdx.y + gy * blockIdx.z);
    const int swz = (flat & 7) * (nwg >> 3) + (flat >> 3);
    int rem = swz, z = 0;
    if (SPLITK) { z = swz / (gx * gy); rem = swz - z * (gx * gy); }
    const int by = rem / gx, bx = rem - by * gx;
    if (SPLITK) { A += (size_t)z * aoff; W += (size_t)z * woff; }
    float* Cf = (SPLITK && z) ? Cf1 : Cf0;

    const int t = threadIdx.x;
    const int w = t >> 6, l = t & 63, l15 = l & 15, lg = l >> 4;
    const int row0 = by * 128, col0 = bx * 128;
    const int wr = (w >> 1) * 64, wc = (w & 1) * 64;

    const int sr = t >> 2;
    const int sc = ((t & 3) ^ ((sr >> 1) & 3)) << 3;
    const bf16* pA0 = A + (size_t)(row0 + sr) * lda + sc;
    const bf16* pA1 = A + (size_t)(row0 + 64 + sr) * lda + sc;
    const bf16* pW0 = W + (size_t)(col0 + sr) * ldw + sc;
    const bf16* pW1 = W + (size_t)(col0 + 64 + sr) * ldw + sc;
    const int lo0 = w * 512, lo1 = 2048 + w * 512;

    auto STAGE = [&](int kt, int slot) {
        bf16* base = (bf16*)LDSp + slot * 8192;
        const int kc = kt * 32;
        GLOAD_LDS16(pA0 + kc, base + lo0);
        GLOAD_LDS16(pA1 + kc, base + lo1);
        GLOAD_LDS16(pW0 + kc, base + 4096 + lo0);
        GLOAD_LDS16(pW1 + kc, base + 4096 + lo1);
    };

    f32x4 acc[4][4];
#pragma unroll
    for (int m = 0; m < 4; ++m)
#pragma unroll
        for (int n = 0; n < 4; ++n) acc[m][n] = f32x4{0.f, 0.f, 0.f, 0.f};

    const int nk = K >> 5;
    STAGE(0, 0); STAGE(1, 1);
    asm volatile("s_waitcnt vmcnt(4)" ::: "memory");
    __builtin_amdgcn_s_barrier();

    int s0 = 0, s1 = 1, s2 = 2;
    const int kcol = (lg ^ ((l15 >> 1) & 3)) << 3;
    for (int kt = 0; kt < nk; ++kt) {
        const bf16* bufA = (const bf16*)LDSp + s0 * 8192;
        const bf16* bufB = bufA + 4096;
        bf16x8 af[4], bf4[4];
#pragma unroll
        for (int m = 0; m < 4; ++m)
            af[m] = *(const bf16x8*)&bufA[(wr + m * 16 + l15) * 32 + kcol];
#pragma unroll
        for (int n = 0; n < 4; ++n)
            bf4[n] = *(const bf16x8*)&bufB[(wc + n * 16 + l15) * 32 + kcol];
        if (kt + 2 < nk) STAGE(kt + 2, s2);
        __builtin_amdgcn_s_setprio(1);
#pragma unroll
        for (int m = 0; m < 4; ++m)
#pragma unroll
            for (int n = 0; n < 4; ++n)
                acc[m][n] = __builtin_amdgcn_mfma_f32_16x16x32_bf16(af[m], bf4[n], acc[m][n], 0, 0, 0);
        __builtin_amdgcn_s_setprio(0);
        asm volatile("s_waitcnt lgkmcnt(0)" ::: "memory");
        __builtin_amdgcn_sched_barrier(0);
        if (kt + 2 < nk) {
            asm volatile("s_waitcnt vmcnt(4)" ::: "memory");
        } else {
            asm volatile("s_waitcnt vmcnt(0)" ::: "memory");
        }
        __builtin_amdgcn_s_barrier();
        const int tmp = s0; s0 = s1; s1 = s2; s2 = tmp;
    }

    if (!SPLITK) {
        float bvn[4];
#pragma unroll
        for (int n = 0; n < 4; ++n) bvn[n] = bias[col0 + wc + n * 16 + l15];
        const int erow = l >> 2, ec = (l & 3) * 16;
#pragma unroll
        for (int m = 0; m < 4; ++m) {
            bf16* ep = (bf16*)LDSp + ((m & 1) * 4 + w) * 1152;
#pragma unroll
            for (int n = 0; n < 4; ++n)
#pragma unroll
                for (int r = 0; r < 4; ++r)
                    ep[(lg * 4 + r) * 72 + n * 16 + l15] = (bf16)(acc[m][n][r] + bvn[n]);
            asm volatile("s_waitcnt lgkmcnt(0)" ::: "memory");
            __builtin_amdgcn_sched_barrier(0);
            bf16x8 v8a = *(const bf16x8*)&ep[erow * 72 + ec];
            bf16x8 v8b = *(const bf16x8*)&ep[erow * 72 + ec + 8];
            const int grow = row0 + wr + m * 16 + erow;
            bf16* dst = Cb + (size_t)grow * ldcb + col0 + wc + ec;
            *(bf16x8*)dst = v8a;
            *(bf16x8*)(dst + 8) = v8b;
        }
    } else {
#pragma unroll
        for (int n = 0; n < 4; ++n) {
            int gcol = col0 + wc + n * 16 + l15;
#pragma unroll
            for (int m = 0; m < 4; ++m) {
                int grow = row0 + wr + m * 16 + lg * 4;
#pragma unroll
                for (int r = 0; r < 4; ++r)
                    Cf[(size_t)(grow + r) * ldcf + gcol] = acc[m][n][r];
            }
        }
    }
}

__global__ __launch_bounds__(256, 2)
void gemmP_outproj_k(const bf16* A, const bf16* W, const float* bias, bf16* Cb) {
    gemmP_body<0>(A, 1024, W, 1024, bias, Cb, 2048, nullptr, nullptr, 0, 1024, 0, 0);
}
__global__ __launch_bounds__(256, 2)
void gemmP_gate2_k(const bf16* A, const bf16* W, float* C0, float* C1) {
    gemmP_body<1>(A, 2048, W, 2048, nullptr, nullptr, 0, C0, C1, 1024, 1024, 1024, 1024);
}
__global__ __launch_bounds__(256, 2)
void gemmP_ffn2_k(const bf16* A, const bf16* W, float* C0, float* C1) {
    gemmP_body<1>(A, 4096, W, 4096, nullptr, nullptr, 0, C0, C1, 1024, 2048, 2048, 2048);
}

// ---------------------------------------------------------------- 128x256 GEMM body (by/bx passed in)
template<int ACT, int ROWBIAS>
__device__ __forceinline__
void gemm128x256_body(int by, int bx,
                      const bf16* __restrict__ A, int lda,
                      const bf16* __restrict__ W, int ldw,
                      const float* __restrict__ bias,
                      bf16* __restrict__ Cb, int ldcb, int K) {
    __shared__ __attribute__((aligned(16))) bf16 LDSb[2][12288];
    const int t = threadIdx.x;
    const int w = t >> 6, l = t & 63, l15 = l & 15, lg = l >> 4;
    const int wrr = w >> 2, wc = w & 3;
    const int row0 = by * 128, col0 = bx * 256;

    const int trow = t >> 2;
    const int scol = ((t & 3) ^ ((trow >> 1) & 3)) << 3;
    const bf16* pA  = A + (size_t)(row0 + trow) * lda + scol;
    const bf16* pB0 = W + (size_t)(col0 + trow) * ldw + scol;
    const bf16* pB1 = W + (size_t)(col0 + 128 + trow) * ldw + scol;
    const int ldsoA  = w * 512;
    const int ldsoB0 = 4096 + w * 512;
    const int ldsoB1 = 8192 + w * 512;

    f32x4 acc[4][4];
#pragma unroll
    for (int m = 0; m < 4; ++m)
#pragma unroll
        for (int n = 0; n < 4; ++n) acc[m][n] = f32x4{0.f, 0.f, 0.f, 0.f};

    const int nk = K >> 5;
    GLOAD_LDS16(pA,  (bf16*)LDSb[0] + ldsoA);
    GLOAD_LDS16(pB0, (bf16*)LDSb[0] + ldsoB0);
    GLOAD_LDS16(pB1, (bf16*)LDSb[0] + ldsoB1);

    for (int kt = 0; kt < nk; ++kt) {
        const int cur = kt & 1;
        if (kt + 1 < nk) {
            const int kc = (kt + 1) * 32;
            bf16* d = (bf16*)LDSb[cur ^ 1];
            GLOAD_LDS16(pA + kc,  d + ldsoA);
            GLOAD_LDS16(pB0 + kc, d + ldsoB0);
            GLOAD_LDS16(pB1 + kc, d + ldsoB1);
            asm volatile("s_waitcnt vmcnt(3)" ::: "memory");
        } else {
            asm volatile("s_waitcnt vmcnt(0)" ::: "memory");
        }
        __builtin_amdgcn_s_barrier();
        const bf16* bufA = (const bf16*)LDSb[cur];
        const bf16* bufB = bufA + 4096;
        const int kcol = (lg ^ ((l15 >> 1) & 3)) << 3;
        bf16x8 bf4[4];
#pragma unroll
        for (int n = 0; n < 4; ++n)
            bf4[n] = *(const bf16x8*)&bufB[(wc * 64 + n * 16 + l15) * 32 + kcol];
#pragma unroll
        for (int m = 0; m < 4; ++m) {
            bf16x8 afm = *(const bf16x8*)&bufA[(wrr * 64 + m * 16 + l15) * 32 + kcol];
#pragma unroll
            for (int n = 0; n < 4; ++n)
                acc[m][n] = __builtin_amdgcn_mfma_f32_16x16x32_bf16(afm, bf4[n], acc[m][n], 0, 0, 0);
        }
        asm volatile("s_waitcnt lgkmcnt(0)" ::: "memory");
        __builtin_amdgcn_sched_barrier(0);
        __builtin_amdgcn_s_barrier();
    }

    const int erow = l >> 2, ec = (l & 3) * 16;
    float bvn[4];
    if (!ROWBIAS) {
#pragma unroll
        for (int n = 0; n < 4; ++n) bvn[n] = bias[col0 + wc * 64 + n * 16 + l15];
    }
#pragma unroll
    for (int m = 0; m < 4; ++m) {
        float bvr[4];
        if (ROWBIAS) {
#pragma unroll
            for (int r = 0; r < 4; ++r)
                bvr[r] = bias[row0 + wrr * 64 + m * 16 + lg * 4 + r];
        }
        bf16* ep = (bf16*)LDSb + ((m & 1) * 8 + w) * 1152;
#pragma unroll
        for (int n = 0; n < 4; ++n)
#pragma unroll
            for (int r = 0; r < 4; ++r) {
                float v = acc[m][n][r] + (ROWBIAS ? bvr[r] : bvn[n]);
                if (ACT) v = gelu_f(v);
                ep[(lg * 4 + r) * 72 + n * 16 + l15] = (bf16)v;
            }
        asm volatile("s_waitcnt lgkmcnt(0)" ::: "memory");
        __builtin_amdgcn_sched_barrier(0);
        bf16x8 v8a = *(const bf16x8*)&ep[erow * 72 + ec];
        bf16x8 v8b = *(const bf16x8*)&ep[erow * 72 + ec + 8];
        const int grow = row0 + wrr * 64 + m * 16 + erow;
        bf16* dst = Cb + (size_t)grow * ldcb + col0 + wc * 64 + ec;
        *(bf16x8*)dst = v8a;
        *(bf16x8*)(dst + 8) = v8b;
    }
}

// merged q/k/vT projections: 640 blocks (256 kproj + 256 vprojT + 128 qproj),
// interleaved fb%5 so each CU holds 2-3 heterogeneous co-resident blocks.
__global__ __launch_bounds__(512, 4)
void gemm_proj3_k(const bf16* __restrict__ xb, const bf16* __restrict__ kvb,
                  const bf16* __restrict__ ipw_b, const float* __restrict__ ipb,
                  bf16* __restrict__ Qp, bf16* __restrict__ Kp, bf16* __restrict__ Vt) {
    const int fb = blockIdx.x;
    const int t5 = fb % 5, g = fb / 5;
    if (t5 == 4) {               // qproj: M=4096 N=1024, A = x_b left half
        const int id = g;        // 0..127
        const int swz = (id & 7) * 16 + (id >> 3);
        gemm128x256_body<0, 0>(swz >> 2, swz & 3, xb, 2048, ipw_b, 1024, ipb, Qp, 1024, 1024);
    } else if (t5 < 2) {         // kproj: M=8192 N=1024
        const int id = g * 2 + t5;               // 0..255
        const int swz = (id & 7) * 32 + (id >> 3);
        gemm128x256_body<0, 0>(swz >> 2, swz & 3, kvb, 1024, ipw_b + 1024 * 1024, 1024,
                               ipb + 1024, Kp, 1024, 1024);
    } else {                     // vprojT: M=1024 N=8192 (row bias) -> V^T
        const int id = g * 2 + (t5 - 2);         // 0..255
        const int swz = (id & 7) * 32 + (id >> 3);
        gemm128x256_body<0, 1>(swz >> 5, swz & 31, ipw_b + 2048 * 1024, 1024, kvb, 1024,
                               ipb + 2048, Vt, 8192, 1024);
    }
}

__global__ __launch_bounds__(512, 4)
void gemmA_ffn1_k(const bf16* A, const bf16* W, const float* bias, bf16* Cb) {
    const int gx = gridDim.x;
    const int nwg = gx * gridDim.y;
    const int flat = blockIdx.x + gx * blockIdx.y;
    const int swz = (flat & 7) * (nwg >> 3) + (flat >> 3);
    gemm128x256_body<1, 0>(swz / gx, swz % gx, A, 1024, W, 1024, bias, Cb, 4096, 1024);
}

// ---------------------------------------------------------------- flash attention + entropy
__device__ __forceinline__ float red16sum(float v) {
    v += __shfl_xor(v, 1, 64);
    v += __shfl_xor(v, 2, 64);
    v += __shfl_xor(v, 4, 64);
    v += __shfl_xor(v, 8, 64);
    return v;
}

__global__ __launch_bounds__(256)
void attn_k(const bf16* __restrict__ Qp, const bf16* __restrict__ Kp,
            const bf16* __restrict__ Vt, bf16* __restrict__ ctx,
            float* __restrict__ entm) {
    __shared__ __attribute__((aligned(16))) bf16 Ks[64 * 64];
    __shared__ __attribute__((aligned(16))) bf16 Vs[64 * 64];
    __shared__ __attribute__((aligned(16))) bf16 Ps[4][16 * 72];
    const int t = threadIdx.x, w = t >> 6, l = t & 63;
    const int l15 = l & 15, lg = l >> 4;
    const int h = blockIdx.x, b = blockIdx.y, qt = blockIdx.z;
    const int qrow0 = b * LQ_ + qt * 64 + w * 16;

    bf16x8 aq[2];
#pragma unroll
    for (int kk = 0; kk < 2; ++kk)
        aq[kk] = *(const bf16x8*)(Qp + (size_t)(qrow0 + l15) * D_ + h * HD_ + kk * 32 + lg * 8);

    const int r0 = t >> 3, r1 = 32 + (t >> 3), j = t & 7;
    const bf16* pK0 = Kp + (size_t)(b * LK_ + r0) * 1024 + h * HD_ + ((j ^ (r0 & 7)) << 3);
    const bf16* pK1 = Kp + (size_t)(b * LK_ + r1) * 1024 + h * HD_ + ((j ^ (r1 & 7)) << 3);
    const bf16* pV0 = Vt + (size_t)(h * HD_ + r0) * (size_t)MK_ + b * LK_ + ((j ^ (r0 & 7)) << 3);
    const bf16* pV1 = Vt + (size_t)(h * HD_ + r1) * (size_t)MK_ + b * LK_ + ((j ^ (r1 & 7)) << 3);
    const int ldsoL = w * 512, ldsoH = 2048 + w * 512;

    auto STAGE = [&](int c) {
        const size_t kadv = (size_t)c * 64 * 1024;
        const size_t vadv = (size_t)c * 64;
        GLOAD_LDS16(pK0 + kadv, (bf16*)Ks + ldsoL);
        GLOAD_LDS16(pK1 + kadv, (bf16*)Ks + ldsoH);
        GLOAD_LDS16(pV0 + vadv, (bf16*)Vs + ldsoL);
        GLOAD_LDS16(pV1 + vadv, (bf16*)Vs + ldsoH);
    };

    f32x4 o[4];
    float Zp[4], S1p[4];
#pragma unroll
    for (int n = 0; n < 4; ++n) o[n] = f32x4{0.f, 0.f, 0.f, 0.f};
#pragma unroll
    for (int r = 0; r < 4; ++r) { Zp[r] = 0.f; S1p[r] = 0.f; }

    const float K1 = 0.125f * LOG2E_;
    const float K0 = -CSHIFT_ * LOG2E_;
    const int swk = l15 & 7;

    for (int c = 0; c < LK_ / 64; ++c) {
        STAGE(c);
        asm volatile("s_waitcnt vmcnt(0)" ::: "memory");
        __builtin_amdgcn_s_barrier();

        f32x4 s[4];
#pragma unroll
        for (int n = 0; n < 4; ++n) {
            s[n] = f32x4{0.f, 0.f, 0.f, 0.f};
#pragma unroll
            for (int kk = 0; kk < 2; ++kk) {
                bf16x8 bk = *(const bf16x8*)&Ks[(n * 16 + l15) * 64 + ((((kk << 2) | lg) ^ swk) << 3)];
                s[n] = __builtin_amdgcn_mfma_f32_16x16x32_bf16(aq[kk], bk, s[n], 0, 0, 0);
            }
        }

        float p[4][4];
#pragma unroll
        for (int r = 0; r < 4; ++r) {
#pragma unroll
            for (int n = 0; n < 4; ++n) {
                float sv = s[n][r];
                float pv = exp2f(fmaf(sv, K1, K0));
                p[n][r] = pv;
                Zp[r] += pv;
                S1p[r] = fmaf(pv, sv, S1p[r]);
            }
        }

#pragma unroll
        for (int r = 0; r < 4; ++r)
#pragma unroll
            for (int n = 0; n < 4; ++n)
                Ps[w][(lg * 4 + r) * 72 + ((n ^ lg) << 4) + l15] = (bf16)p[n][r];

        bf16x8 ap[2];
#pragma unroll
        for (int kk = 0; kk < 2; ++kk)
            ap[kk] = *(const bf16x8*)&Ps[w][l15 * 72 + ((kk * 32 + lg * 8) ^ (((l15 >> 2) & 3) << 4))];
#pragma unroll
        for (int n = 0; n < 4; ++n)
#pragma unroll
            for (int kk = 0; kk < 2; ++kk) {
                bf16x8 bv = *(const bf16x8*)&Vs[(n * 16 + l15) * 64 + ((((kk << 2) | lg) ^ swk) << 3)];
                o[n] = __builtin_amdgcn_mfma_f32_16x16x32_bf16(ap[kk], bv, o[n], 0, 0, 0);
            }

        asm volatile("s_waitcnt lgkmcnt(0)" ::: "memory");
        __builtin_amdgcn_sched_barrier(0);
        __builtin_amdgcn_s_barrier();
    }

#pragma unroll
    for (int r = 0; r < 4; ++r) {
        float Zr = red16sum(Zp[r]);
        float S1r = red16sum(S1p[r]) * 0.125f;
        float inv = 1.0f / Zr;
        int grow = qrow0 + lg * 4 + r;
#pragma unroll
        for (int n = 0; n < 4; ++n)
            ctx[(size_t)grow * D_ + h * HD_ + n * 16 + l15] = (bf16)(o[n][r] * inv);
        if (l15 == 0) {
            float ent = (CSHIFT_ + logf(Zr) - S1r * inv) * INV_LN_LK_ * (1.0f / 16.0f);
            atomicAdd(&entm[grow], ent);
        }
    }
}

// ---------------------------------------------------------------- block reductions
__device__ __forceinline__ float blk_sum(float v, float* sb) {
#pragma unroll
    for (int m = 1; m < 64; m <<= 1) v += __shfl_xor(v, m, 64);
    int w = threadIdx.x >> 6;
    __syncthreads();
    if ((threadIdx.x & 63) == 0) sb[w] = v;
    __syncthreads();
    return sb[0] + sb[1] + sb[2] + sb[3];
}
__device__ __forceinline__ float2 blk_sum2(float2 v, float* sb) {
#pragma unroll
    for (int m = 1; m < 64; m <<= 1) {
        v.x += __shfl_xor(v.x, m, 64);
        v.y += __shfl_xor(v.y, m, 64);
    }
    int w = threadIdx.x >> 6;
    __syncthreads();
    if ((threadIdx.x & 63) == 0) { sb[w * 2] = v.x; sb[w * 2 + 1] = v.y; }
    __syncthreads();
    return make_float2(sb[0] + sb[2] + sb[4] + sb[6], sb[1] + sb[3] + sb[5] + sb[7]);
}

// ---------------------------------------------------------------- gate + first LN (one row/block)
__global__ __launch_bounds__(256)
void gate_ln1_k(const float* __restrict__ qin, const bf16* __restrict__ xb,
                const float* __restrict__ gp0, const float* __restrict__ gp1,
                const float* __restrict__ gb1, const float* __restrict__ gw2,
                const float* __restrict__ gb2, const float* __restrict__ entm,
                const float* __restrict__ lng, const float* __restrict__ lnb,
                bf16* __restrict__ q2b) {
    __shared__ float sb[8];
    const int row = blockIdx.x, t = threadIdx.x, c0 = t * 4;
    float4 p0 = *(const float4*)(gp0 + (size_t)row * D_ + c0);
    float4 p1 = *(const float4*)(gp1 + (size_t)row * D_ + c0);
    float4 hb = *(const float4*)(gb1 + c0);
    float h0 = gelu_f(p0.x + p1.x + hb.x);
    float h1 = gelu_f(p0.y + p1.y + hb.y);
    float h2 = gelu_f(p0.z + p1.z + hb.z);
    float h3 = gelu_f(p0.w + p1.w + hb.w);
    float4 g4 = *(const float4*)(gw2 + c0);
    float dot = h0 * g4.x + h1 * g4.y + h2 * g4.z + h3 * g4.w;
    dot = blk_sum(dot, sb);
    float g = 1.0f / (1.0f + expf(-(dot + gb2[0])));
    float conf = fminf(fmaxf(1.0f - entm[row], 0.0f), 1.0f);
    g *= conf;
    float4 qv = *(const float4*)(qin + (size_t)row * D_ + c0);
    bf16x4 a4 = *(const bf16x4*)(xb + (size_t)row * 2048 + 1024 + c0);
    float y[4] = { qv.x + (float)a4[0] * g, qv.y + (float)a4[1] * g,
                   qv.z + (float)a4[2] * g, qv.w + (float)a4[3] * g };
    float2 ss = blk_sum2(make_float2(y[0] + y[1] + y[2] + y[3],
                                     y[0]*y[0] + y[1]*y[1] + y[2]*y[2] + y[3]*y[3]), sb);
    float mu = ss.x * (1.0f / D_);
    float var = ss.y * (1.0f / D_) - mu * mu;
    float rs = rsqrtf(var + 1e-5f);
    float4 gg = *(const float4*)(lng + c0);
    float4 bb = *(const float4*)(lnb + c0);
    bf16x4 ob;
    ob[0] = (bf16)((y[0] - mu) * rs * gg.x + bb.x);
    ob[1] = (bf16)((y[1] - mu) * rs * gg.y + bb.y);
    ob[2] = (bf16)((y[2] - mu) * rs * gg.z + bb.z);
    ob[3] = (bf16)((y[3] - mu) * rs * gg.w + bb.w);
    *(bf16x4*)(q2b + (size_t)row * D_ + c0) = ob;
}

// ---------------------------------------------------------------- residual(bf16) + ffn partials + LN -> out
__global__ __launch_bounds__(256)
void ln2_k(const bf16* __restrict__ q2b, const float* __restrict__ fp0,
           const float* __restrict__ fp1, const float* __restrict__ b2,
           const float* __restrict__ lng, const float* __restrict__ lnb,
           float* __restrict__ outp) {
    __shared__ float sb[8];
    const int row = blockIdx.x, t = threadIdx.x, c0 = t * 4;
    bf16x4 a4 = *(const bf16x4*)(q2b + (size_t)row * D_ + c0);
    float4 f0 = *(const float4*)(fp0 + (size_t)row * D_ + c0);
    float4 f1 = *(const float4*)(fp1 + (size_t)row * D_ + c0);
    float4 bv = *(const float4*)(b2 + c0);
    float y[4] = { (float)a4[0] + f0.x + f1.x + bv.x, (float)a4[1] + f0.y + f1.y + bv.y,
                   (float)a4[2] + f0.z + f1.z + bv.z, (float)a4[3] + f0.w + f1.w + bv.w };
    float2 ss = blk_sum2(make_float2(y[0] + y[1] + y[2] + y[3],
                                     y[0]*y[0] + y[1]*y[1] + y[2]*y[2] + y[3]*y[3]), sb);
    float mu = ss.x * (1.0f / D_);
    float var = ss.y * (1.0f / D_) - mu * mu;
    float rs = rsqrtf(var + 1e-5f);
    float4 gg = *(const float4*)(lng + c0);
    float4 bb = *(const float4*)(lnb + c0);
    *(float4*)(outp + (size_t)row * D_ + c0) = make_float4(
        (y[0] - mu) * rs * gg.x + bb.x, (y[1] - mu) * rs * gg.y + bb.y,
        (y[2] - mu) * rs * gg.z + bb.z, (y[3] - mu) * rs * gg.w + bb.w);
}

// ---------------------------------------------------------------- launch
extern "C" void kernel_launch(void* const* d_in, const int* in_sizes, int n_in,
                              void* d_out, int out_size, void* d_ws, size_t ws_size,
                              hipStream_t stream) {
    (void)in_sizes; (void)n_in; (void)out_size; (void)ws_size;
    const float* q    = (const float*)d_in[0];
    const float* kv   = (const float*)d_in[2];
    const float* ipw  = (const float*)d_in[4];
    const float* ipb  = (const float*)d_in[5];
    const float* outw = (const float*)d_in[6];
    const float* outb = (const float*)d_in[7];
    const float* lng  = (const float*)d_in[8];
    const float* lnb  = (const float*)d_in[9];
    const float* w1   = (const float*)d_in[10];
    const float* b1   = (const float*)d_in[11];
    const float* w2   = (const float*)d_in[12];
    const float* b2   = (const float*)d_in[13];
    const float* gw1  = (const float*)d_in[14];
    const float* gb1  = (const float*)d_in[15];
    const float* gw2  = (const float*)d_in[16];
    const float* gb2  = (const float*)d_in[17];

    char* ws = (char*)d_ws;
    const size_t MB = 1u << 20;
    bf16*  ipw_b  = (bf16*)(ws + 0);         // [0,6)
    bf16*  outw_b = (bf16*)(ws + 6 * MB);    // [6,8)
    bf16*  w1_b   = (bf16*)(ws + 8 * MB);    // [8,16)
    bf16*  w2_b   = (bf16*)(ws + 16 * MB);   // [16,24)
    bf16*  gw1_b  = (bf16*)(ws + 24 * MB);   // [24,28)
    bf16*  x_b    = (bf16*)(ws + 28 * MB);   // [28,44)  4096x2048 [q | attn_out]
    bf16*  kv_b   = (bf16*)(ws + 44 * MB);   // [44,60)
    bf16*  Qp     = (bf16*)(ws + 60 * MB);   // [60,68)
    bf16*  Kp     = (bf16*)(ws + 68 * MB);   // [68,84)  [8192][1024]
    bf16*  Vt     = (bf16*)(ws + 84 * MB);   // [84,100) [1024][8192] = V^T
    bf16*  ctx    = (bf16*)(ws + 100 * MB);  // [100,108)
    // reuse (lifetimes disjoint):
    float* gp0    = (float*)(ws + 44 * MB);  // [44,60)  over kv_b
    float* gp1    = (float*)(ws + 60 * MB);  // [60,76)  over Qp + Kp-head
    bf16*  q2b    = (bf16*)(ws + 100 * MB);  // [100,108) over ctx
    bf16*  h1     = (bf16*)(ws + 44 * MB);   // [44,76)  over gp0/gp1
    float* fp0    = (float*)(ws + 28 * MB);  // [28,44)  over x_b
    float* fp1    = (float*)(ws + 0);        // [0,16)   over ipw/outw/w1_b

    float* out  = (float*)d_out;
    float* entm = out + (size_t)MQ_ * D_;

    (void)hipMemsetAsync(entm, 0, (size_t)MQ_ * sizeof(float), stream);

    cast_all_k<<<13312, 256, 0, stream>>>(ipw, outw, w1, w2, gw1, q, kv,
                                          ipw_b, outw_b, w1_b, w2_b, gw1_b, x_b, kv_b);

    gemm_proj3_k<<<640, 512, 0, stream>>>(x_b, kv_b, ipw_b, ipb, Qp, Kp, Vt);
    attn_k<<<dim3(H_, B_, LQ_ / 64), 256, 0, stream>>>(Qp, Kp, Vt, ctx, entm);
    gemmP_outproj_k<<<dim3(8, 32), 256, 0, stream>>>(ctx, outw_b, outb, x_b + 1024);
    gemmP_gate2_k<<<dim3(8, 32, 2), 256, 0, stream>>>(x_b, gw1_b, gp0, gp1);
    gate_ln1_k<<<MQ_, 256, 0, stream>>>(q, x_b, gp0, gp1, gb1, gw2, gb2, entm, lng, lnb, q2b);
    gemmA_ffn1_k<<<dim3(16, 32), 512, 0, stream>>>(q2b, w1_b, b1, h1);
    gemmP_ffn2_k<<<dim3(8, 32, 2), 256, 0, stream>>>(h1, w2_b, fp0, fp1);
    ln2_k<<<MQ_, 256, 0, stream>>>(q2b, fp0, fp1, b2, lng, lnb, out);
}

// Round 13
// 282.407 us; speedup vs baseline: 1.1098x; 1.1098x over previous
//
#include <hip/hip_runtime.h>
#include <cstdint>
#include <cstddef>

typedef __bf16 bf16;
typedef __bf16 bf16x8 __attribute__((ext_vector_type(8)));
typedef __bf16 bf16x4 __attribute__((ext_vector_type(4)));
typedef float  f32x4  __attribute__((ext_vector_type(4)));

#define GLOAD_LDS16(g, l) __builtin_amdgcn_global_load_lds( \
    (const __attribute__((address_space(1))) unsigned int*)(g), \
    (__attribute__((address_space(3))) unsigned int*)(l), 16, 0, 0)

static constexpr int D_  = 1024;
static constexpr int H_  = 16;
static constexpr int HD_ = 64;
static constexpr int B_  = 8;
static constexpr int LQ_ = 512;
static constexpr int LK_ = 1024;
static constexpr int MQ_ = B_ * LQ_;   // 4096 query rows
static constexpr int MK_ = B_ * LK_;   // 8192 kv rows
static constexpr float LOG2E_ = 1.4426950408889634f;
static constexpr float INV_LN_LK_ = 0.14426950408889634f; // 1/ln(1024)
static constexpr float CSHIFT_ = 8.0f;                    // fixed softmax shift

// fast gelu (tanh form, folded to x*sigmoid(2z)); |err vs erf-gelu| <= ~1e-3
__device__ __forceinline__ float gelu_f(float v) {
    float v2 = v * v;
    float u = fmaf(0.035677408136f, v2, 0.7978845608028654f);
    float s = exp2f(v * u * -2.8853900817779268f);
    return v / (1.0f + s);
}

// ---------------------------------------------------------------- fused casts
__global__ __launch_bounds__(256)
void cast_all_k(const float* __restrict__ ipw, const float* __restrict__ outw,
                const float* __restrict__ w1,  const float* __restrict__ w2,
                const float* __restrict__ gw1, const float* __restrict__ q,
                const float* __restrict__ kv,
                bf16* __restrict__ ipw_b, bf16* __restrict__ outw_b,
                bf16* __restrict__ w1_b,  bf16* __restrict__ w2_b,
                bf16* __restrict__ gw1_b, bf16* __restrict__ x_b,
                bf16* __restrict__ kv_b) {
    const int b = blockIdx.x, t = threadIdx.x;
    const float* src; bf16* dst; long e;
    if (b < 1536)       { src = ipw;  dst = ipw_b;  e = (long)b * 2048; }
    else if (b < 2048)  { src = outw; dst = outw_b; e = (long)(b - 1536) * 2048; }
    else if (b < 4096)  { src = w1;   dst = w1_b;   e = (long)(b - 2048) * 2048; }
    else if (b < 6144)  { src = w2;   dst = w2_b;   e = (long)(b - 4096) * 2048; }
    else if (b < 7168)  { src = gw1;  dst = gw1_b;  e = (long)(b - 6144) * 2048; }
    else if (b < 11264) { src = kv;   dst = kv_b;   e = (long)(b - 7168) * 2048; }
    else {  // q: strided write into x_b left half (dld 2048)
        long e2 = (long)(b - 11264) * 2048 + t * 8;
        float4 a = *(const float4*)(q + e2);
        float4 c = *(const float4*)(q + e2 + 4);
        bf16x8 o;
        o[0]=(bf16)a.x; o[1]=(bf16)a.y; o[2]=(bf16)a.z; o[3]=(bf16)a.w;
        o[4]=(bf16)c.x; o[5]=(bf16)c.y; o[6]=(bf16)c.z; o[7]=(bf16)c.w;
        long row = e2 >> 10, col = e2 & 1023;
        *(bf16x8*)(x_b + row * 2048 + col) = o;
        return;
    }
    e += t * 8;
    float4 a = *(const float4*)(src + e);
    float4 c = *(const float4*)(src + e + 4);
    bf16x8 o;
    o[0]=(bf16)a.x; o[1]=(bf16)a.y; o[2]=(bf16)a.z; o[3]=(bf16)a.w;
    o[4]=(bf16)c.x; o[5]=(bf16)c.y; o[6]=(bf16)c.z; o[7]=(bf16)c.w;
    *(bf16x8*)(dst + e) = o;
}

// ---------------------------------------------------------------- 128x128 pipelined GEMM (gemmP)
template<int SPLITK>
__device__ __forceinline__
void gemmP_body(const bf16* __restrict__ A, int lda,
                const bf16* __restrict__ W, int ldw,
                const float* __restrict__ bias,
                bf16* __restrict__ Cb, int ldcb,
                float* __restrict__ Cf0, float* __restrict__ Cf1, int ldcf,
                int K, int aoff, int woff) {
    __shared__ __attribute__((aligned(16))) bf16 LDSp[3 * 8192];
    const int gx = gridDim.x, gy = gridDim.y;
    const int nwg = gx * gy * gridDim.z;
    const int flat = blockIdx.x + gx * (blockIdx.y + gy * blockIdx.z);
    const int swz = (flat & 7) * (nwg >> 3) + (flat >> 3);
    int rem = swz, z = 0;
    if (SPLITK) { z = swz / (gx * gy); rem = swz - z * (gx * gy); }
    const int by = rem / gx, bx = rem - by * gx;
    if (SPLITK) { A += (size_t)z * aoff; W += (size_t)z * woff; }
    float* Cf = (SPLITK && z) ? Cf1 : Cf0;

    const int t = threadIdx.x;
    const int w = t >> 6, l = t & 63, l15 = l & 15, lg = l >> 4;
    const int row0 = by * 128, col0 = bx * 128;
    const int wr = (w >> 1) * 64, wc = (w & 1) * 64;

    const int sr = t >> 2;
    const int sc = ((t & 3) ^ ((sr >> 1) & 3)) << 3;
    const bf16* pA0 = A + (size_t)(row0 + sr) * lda + sc;
    const bf16* pA1 = A + (size_t)(row0 + 64 + sr) * lda + sc;
    const bf16* pW0 = W + (size_t)(col0 + sr) * ldw + sc;
    const bf16* pW1 = W + (size_t)(col0 + 64 + sr) * ldw + sc;
    const int lo0 = w * 512, lo1 = 2048 + w * 512;

    auto STAGE = [&](int kt, int slot) {
        bf16* base = (bf16*)LDSp + slot * 8192;
        const int kc = kt * 32;
        GLOAD_LDS16(pA0 + kc, base + lo0);
        GLOAD_LDS16(pA1 + kc, base + lo1);
        GLOAD_LDS16(pW0 + kc, base + 4096 + lo0);
        GLOAD_LDS16(pW1 + kc, base + 4096 + lo1);
    };

    f32x4 acc[4][4];
#pragma unroll
    for (int m = 0; m < 4; ++m)
#pragma unroll
        for (int n = 0; n < 4; ++n) acc[m][n] = f32x4{0.f, 0.f, 0.f, 0.f};

    const int nk = K >> 5;
    STAGE(0, 0); STAGE(1, 1);
    asm volatile("s_waitcnt vmcnt(4)" ::: "memory");
    __builtin_amdgcn_s_barrier();

    int s0 = 0, s1 = 1, s2 = 2;
    const int kcol = (lg ^ ((l15 >> 1) & 3)) << 3;
    for (int kt = 0; kt < nk; ++kt) {
        const bf16* bufA = (const bf16*)LDSp + s0 * 8192;
        const bf16* bufB = bufA + 4096;
        bf16x8 af[4], bf4[4];
#pragma unroll
        for (int m = 0; m < 4; ++m)
            af[m] = *(const bf16x8*)&bufA[(wr + m * 16 + l15) * 32 + kcol];
#pragma unroll
        for (int n = 0; n < 4; ++n)
            bf4[n] = *(const bf16x8*)&bufB[(wc + n * 16 + l15) * 32 + kcol];
        if (kt + 2 < nk) STAGE(kt + 2, s2);
        __builtin_amdgcn_s_setprio(1);
#pragma unroll
        for (int m = 0; m < 4; ++m)
#pragma unroll
            for (int n = 0; n < 4; ++n)
                acc[m][n] = __builtin_amdgcn_mfma_f32_16x16x32_bf16(af[m], bf4[n], acc[m][n], 0, 0, 0);
        __builtin_amdgcn_s_setprio(0);
        asm volatile("s_waitcnt lgkmcnt(0)" ::: "memory");
        __builtin_amdgcn_sched_barrier(0);
        if (kt + 2 < nk) {
            asm volatile("s_waitcnt vmcnt(4)" ::: "memory");
        } else {
            asm volatile("s_waitcnt vmcnt(0)" ::: "memory");
        }
        __builtin_amdgcn_s_barrier();
        const int tmp = s0; s0 = s1; s1 = s2; s2 = tmp;
    }

    if (!SPLITK) {
        float bvn[4];
#pragma unroll
        for (int n = 0; n < 4; ++n) bvn[n] = bias[col0 + wc + n * 16 + l15];
        const int erow = l >> 2, ec = (l & 3) * 16;
#pragma unroll
        for (int m = 0; m < 4; ++m) {
            bf16* ep = (bf16*)LDSp + ((m & 1) * 4 + w) * 1152;
#pragma unroll
            for (int n = 0; n < 4; ++n)
#pragma unroll
                for (int r = 0; r < 4; ++r)
                    ep[(lg * 4 + r) * 72 + n * 16 + l15] = (bf16)(acc[m][n][r] + bvn[n]);
            asm volatile("s_waitcnt lgkmcnt(0)" ::: "memory");
            __builtin_amdgcn_sched_barrier(0);
            bf16x8 v8a = *(const bf16x8*)&ep[erow * 72 + ec];
            bf16x8 v8b = *(const bf16x8*)&ep[erow * 72 + ec + 8];
            const int grow = row0 + wr + m * 16 + erow;
            bf16* dst = Cb + (size_t)grow * ldcb + col0 + wc + ec;
            *(bf16x8*)dst = v8a;
            *(bf16x8*)(dst + 8) = v8b;
        }
    } else {
#pragma unroll
        for (int n = 0; n < 4; ++n) {
            int gcol = col0 + wc + n * 16 + l15;
#pragma unroll
            for (int m = 0; m < 4; ++m) {
                int grow = row0 + wr + m * 16 + lg * 4;
#pragma unroll
                for (int r = 0; r < 4; ++r)
                    Cf[(size_t)(grow + r) * ldcf + gcol] = acc[m][n][r];
            }
        }
    }
}

__global__ __launch_bounds__(256, 2)
void gemmP_outproj_k(const bf16* A, const bf16* W, const float* bias, bf16* Cb) {
    gemmP_body<0>(A, 1024, W, 1024, bias, Cb, 2048, nullptr, nullptr, 0, 1024, 0, 0);
}
__global__ __launch_bounds__(256, 2)
void gemmP_gate2_k(const bf16* A, const bf16* W, float* C0, float* C1) {
    gemmP_body<1>(A, 2048, W, 2048, nullptr, nullptr, 0, C0, C1, 1024, 1024, 1024, 1024);
}
__global__ __launch_bounds__(256, 2)
void gemmP_ffn2_k(const bf16* A, const bf16* W, float* C0, float* C1) {
    gemmP_body<1>(A, 4096, W, 4096, nullptr, nullptr, 0, C0, C1, 1024, 2048, 2048, 2048);
}

// ---------------------------------------------------------------- 128x256 GEMM body (LDS passed in)
template<int ACT, int ROWBIAS>
__device__ __forceinline__
void gemm128x256_body(bf16* LDSb, int by, int bx,
                      const bf16* __restrict__ A, int lda,
                      const bf16* __restrict__ W, int ldw,
                      const float* __restrict__ bias,
                      bf16* __restrict__ Cb, int ldcb, int K) {
    const int t = threadIdx.x;
    const int w = t >> 6, l = t & 63, l15 = l & 15, lg = l >> 4;
    const int wrr = w >> 2, wc = w & 3;
    const int row0 = by * 128, col0 = bx * 256;

    const int trow = t >> 2;
    const int scol = ((t & 3) ^ ((trow >> 1) & 3)) << 3;
    const bf16* pA  = A + (size_t)(row0 + trow) * lda + scol;
    const bf16* pB0 = W + (size_t)(col0 + trow) * ldw + scol;
    const bf16* pB1 = W + (size_t)(col0 + 128 + trow) * ldw + scol;
    const int ldsoA  = w * 512;
    const int ldsoB0 = 4096 + w * 512;
    const int ldsoB1 = 8192 + w * 512;

    f32x4 acc[4][4];
#pragma unroll
    for (int m = 0; m < 4; ++m)
#pragma unroll
        for (int n = 0; n < 4; ++n) acc[m][n] = f32x4{0.f, 0.f, 0.f, 0.f};

    const int nk = K >> 5;
    GLOAD_LDS16(pA,  LDSb + ldsoA);
    GLOAD_LDS16(pB0, LDSb + ldsoB0);
    GLOAD_LDS16(pB1, LDSb + ldsoB1);

    for (int kt = 0; kt < nk; ++kt) {
        const int cur = kt & 1;
        if (kt + 1 < nk) {
            const int kc = (kt + 1) * 32;
            bf16* d = LDSb + (cur ^ 1) * 12288;
            GLOAD_LDS16(pA + kc,  d + ldsoA);
            GLOAD_LDS16(pB0 + kc, d + ldsoB0);
            GLOAD_LDS16(pB1 + kc, d + ldsoB1);
            asm volatile("s_waitcnt vmcnt(3)" ::: "memory");
        } else {
            asm volatile("s_waitcnt vmcnt(0)" ::: "memory");
        }
        __builtin_amdgcn_s_barrier();
        const bf16* bufA = LDSb + cur * 12288;
        const bf16* bufB = bufA + 4096;
        const int kcol = (lg ^ ((l15 >> 1) & 3)) << 3;
        bf16x8 bf4[4];
#pragma unroll
        for (int n = 0; n < 4; ++n)
            bf4[n] = *(const bf16x8*)&bufB[(wc * 64 + n * 16 + l15) * 32 + kcol];
#pragma unroll
        for (int m = 0; m < 4; ++m) {
            bf16x8 afm = *(const bf16x8*)&bufA[(wrr * 64 + m * 16 + l15) * 32 + kcol];
#pragma unroll
            for (int n = 0; n < 4; ++n)
                acc[m][n] = __builtin_amdgcn_mfma_f32_16x16x32_bf16(afm, bf4[n], acc[m][n], 0, 0, 0);
        }
        asm volatile("s_waitcnt lgkmcnt(0)" ::: "memory");
        __builtin_amdgcn_sched_barrier(0);
        __builtin_amdgcn_s_barrier();
    }

    const int erow = l >> 2, ec = (l & 3) * 16;
    float bvn[4];
    if (!ROWBIAS) {
#pragma unroll
        for (int n = 0; n < 4; ++n) bvn[n] = bias[col0 + wc * 64 + n * 16 + l15];
    }
#pragma unroll
    for (int m = 0; m < 4; ++m) {
        float bvr[4];
        if (ROWBIAS) {
#pragma unroll
            for (int r = 0; r < 4; ++r)
                bvr[r] = bias[row0 + wrr * 64 + m * 16 + lg * 4 + r];
        }
        bf16* ep = LDSb + ((m & 1) * 8 + w) * 1152;
#pragma unroll
        for (int n = 0; n < 4; ++n)
#pragma unroll
            for (int r = 0; r < 4; ++r) {
                float v = acc[m][n][r] + (ROWBIAS ? bvr[r] : bvn[n]);
                if (ACT) v = gelu_f(v);
                ep[(lg * 4 + r) * 72 + n * 16 + l15] = (bf16)v;
            }
        asm volatile("s_waitcnt lgkmcnt(0)" ::: "memory");
        __builtin_amdgcn_sched_barrier(0);
        bf16x8 v8a = *(const bf16x8*)&ep[erow * 72 + ec];
        bf16x8 v8b = *(const bf16x8*)&ep[erow * 72 + ec + 8];
        const int grow = row0 + wrr * 64 + m * 16 + erow;
        bf16* dst = Cb + (size_t)grow * ldcb + col0 + wc * 64 + ec;
        *(bf16x8*)dst = v8a;
        *(bf16x8*)(dst + 8) = v8b;
    }
}

// merged q/k/vT projections: contiguous ranges [0,256) kproj | [256,512) vprojT | [512,640) qproj.
// One 48 KB LDS array -> 3 blocks/CU capacity; in-order dispatch co-locates one of each per CU.
__global__ __launch_bounds__(512, 4)
void gemm_proj3_k(const bf16* __restrict__ xb, const bf16* __restrict__ kvb,
                  const bf16* __restrict__ ipw_b, const float* __restrict__ ipb,
                  bf16* __restrict__ Qp, bf16* __restrict__ Kp, bf16* __restrict__ Vt) {
    __shared__ __attribute__((aligned(16))) bf16 LDSb[2 * 12288];
    const int fb = blockIdx.x;
    if (fb < 256) {              // kproj: M=8192 N=1024 -> grid 64(by) x 4(bx)
        const int id = fb;
        const int swz = (id & 7) * 32 + (id >> 3);
        gemm128x256_body<0, 0>(LDSb, swz >> 2, swz & 3, kvb, 1024, ipw_b + 1024 * 1024, 1024,
                               ipb + 1024, Kp, 1024, 1024);
    } else if (fb < 512) {       // vprojT: M=1024 N=8192 (row bias) -> grid 8(by) x 32(bx)
        const int id = fb - 256;
        const int swz = (id & 7) * 32 + (id >> 3);
        gemm128x256_body<0, 1>(LDSb, swz >> 5, swz & 31, ipw_b + 2048 * 1024, 1024, kvb, 1024,
                               ipb + 2048, Vt, 8192, 1024);
    } else {                     // qproj: M=4096 N=1024 -> grid 32(by) x 4(bx)
        const int id = fb - 512; // 0..127
        const int swz = (id & 7) * 16 + (id >> 3);
        gemm128x256_body<0, 0>(LDSb, swz >> 2, swz & 3, xb, 2048, ipw_b, 1024, ipb, Qp, 1024, 1024);
    }
}

__global__ __launch_bounds__(512, 4)
void gemmA_ffn1_k(const bf16* A, const bf16* W, const float* bias, bf16* Cb) {
    __shared__ __attribute__((aligned(16))) bf16 LDSb[2 * 12288];
    const int gx = gridDim.x;
    const int nwg = gx * gridDim.y;
    const int flat = blockIdx.x + gx * blockIdx.y;
    const int swz = (flat & 7) * (nwg >> 3) + (flat >> 3);
    gemm128x256_body<1, 0>(LDSb, swz / gx, swz % gx, A, 1024, W, 1024, bias, Cb, 4096, 1024);
}

// ---------------------------------------------------------------- flash attention + entropy
__device__ __forceinline__ float red16sum(float v) {
    v += __shfl_xor(v, 1, 64);
    v += __shfl_xor(v, 2, 64);
    v += __shfl_xor(v, 4, 64);
    v += __shfl_xor(v, 8, 64);
    return v;
}

__global__ __launch_bounds__(256)
void attn_k(const bf16* __restrict__ Qp, const bf16* __restrict__ Kp,
            const bf16* __restrict__ Vt, bf16* __restrict__ ctx,
            float* __restrict__ entm) {
    __shared__ __attribute__((aligned(16))) bf16 Ks[64 * 64];
    __shared__ __attribute__((aligned(16))) bf16 Vs[64 * 64];
    __shared__ __attribute__((aligned(16))) bf16 Ps[4][16 * 72];
    const int t = threadIdx.x, w = t >> 6, l = t & 63;
    const int l15 = l & 15, lg = l >> 4;
    const int h = blockIdx.x, b = blockIdx.y, qt = blockIdx.z;
    const int qrow0 = b * LQ_ + qt * 64 + w * 16;

    bf16x8 aq[2];
#pragma unroll
    for (int kk = 0; kk < 2; ++kk)
        aq[kk] = *(const bf16x8*)(Qp + (size_t)(qrow0 + l15) * D_ + h * HD_ + kk * 32 + lg * 8);

    const int r0 = t >> 3, r1 = 32 + (t >> 3), j = t & 7;
    const bf16* pK0 = Kp + (size_t)(b * LK_ + r0) * 1024 + h * HD_ + ((j ^ (r0 & 7)) << 3);
    const bf16* pK1 = Kp + (size_t)(b * LK_ + r1) * 1024 + h * HD_ + ((j ^ (r1 & 7)) << 3);
    const bf16* pV0 = Vt + (size_t)(h * HD_ + r0) * (size_t)MK_ + b * LK_ + ((j ^ (r0 & 7)) << 3);
    const bf16* pV1 = Vt + (size_t)(h * HD_ + r1) * (size_t)MK_ + b * LK_ + ((j ^ (r1 & 7)) << 3);
    const int ldsoL = w * 512, ldsoH = 2048 + w * 512;

    auto STAGE = [&](int c) {
        const size_t kadv = (size_t)c * 64 * 1024;
        const size_t vadv = (size_t)c * 64;
        GLOAD_LDS16(pK0 + kadv, (bf16*)Ks + ldsoL);
        GLOAD_LDS16(pK1 + kadv, (bf16*)Ks + ldsoH);
        GLOAD_LDS16(pV0 + vadv, (bf16*)Vs + ldsoL);
        GLOAD_LDS16(pV1 + vadv, (bf16*)Vs + ldsoH);
    };

    f32x4 o[4];
    float Zp[4], S1p[4];
#pragma unroll
    for (int n = 0; n < 4; ++n) o[n] = f32x4{0.f, 0.f, 0.f, 0.f};
#pragma unroll
    for (int r = 0; r < 4; ++r) { Zp[r] = 0.f; S1p[r] = 0.f; }

    const float K1 = 0.125f * LOG2E_;
    const float K0 = -CSHIFT_ * LOG2E_;
    const int swk = l15 & 7;

    for (int c = 0; c < LK_ / 64; ++c) {
        STAGE(c);
        asm volatile("s_waitcnt vmcnt(0)" ::: "memory");
        __builtin_amdgcn_s_barrier();

        f32x4 s[4];
#pragma unroll
        for (int n = 0; n < 4; ++n) {
            s[n] = f32x4{0.f, 0.f, 0.f, 0.f};
#pragma unroll
            for (int kk = 0; kk < 2; ++kk) {
                bf16x8 bk = *(const bf16x8*)&Ks[(n * 16 + l15) * 64 + ((((kk << 2) | lg) ^ swk) << 3)];
                s[n] = __builtin_amdgcn_mfma_f32_16x16x32_bf16(aq[kk], bk, s[n], 0, 0, 0);
            }
        }

        float p[4][4];
#pragma unroll
        for (int r = 0; r < 4; ++r) {
#pragma unroll
            for (int n = 0; n < 4; ++n) {
                float sv = s[n][r];
                float pv = exp2f(fmaf(sv, K1, K0));
                p[n][r] = pv;
                Zp[r] += pv;
                S1p[r] = fmaf(pv, sv, S1p[r]);
            }
        }

#pragma unroll
        for (int r = 0; r < 4; ++r)
#pragma unroll
            for (int n = 0; n < 4; ++n)
                Ps[w][(lg * 4 + r) * 72 + ((n ^ lg) << 4) + l15] = (bf16)p[n][r];

        bf16x8 ap[2];
#pragma unroll
        for (int kk = 0; kk < 2; ++kk)
            ap[kk] = *(const bf16x8*)&Ps[w][l15 * 72 + ((kk * 32 + lg * 8) ^ (((l15 >> 2) & 3) << 4))];
#pragma unroll
        for (int n = 0; n < 4; ++n)
#pragma unroll
            for (int kk = 0; kk < 2; ++kk) {
                bf16x8 bv = *(const bf16x8*)&Vs[(n * 16 + l15) * 64 + ((((kk << 2) | lg) ^ swk) << 3)];
                o[n] = __builtin_amdgcn_mfma_f32_16x16x32_bf16(ap[kk], bv, o[n], 0, 0, 0);
            }

        asm volatile("s_waitcnt lgkmcnt(0)" ::: "memory");
        __builtin_amdgcn_sched_barrier(0);
        __builtin_amdgcn_s_barrier();
    }

#pragma unroll
    for (int r = 0; r < 4; ++r) {
        float Zr = red16sum(Zp[r]);
        float S1r = red16sum(S1p[r]) * 0.125f;
        float inv = 1.0f / Zr;
        int grow = qrow0 + lg * 4 + r;
#pragma unroll
        for (int n = 0; n < 4; ++n)
            ctx[(size_t)grow * D_ + h * HD_ + n * 16 + l15] = (bf16)(o[n][r] * inv);
        if (l15 == 0) {
            float ent = (CSHIFT_ + logf(Zr) - S1r * inv) * INV_LN_LK_ * (1.0f / 16.0f);
            atomicAdd(&entm[grow], ent);
        }
    }
}

// ---------------------------------------------------------------- block reductions
__device__ __forceinline__ float blk_sum(float v, float* sb) {
#pragma unroll
    for (int m = 1; m < 64; m <<= 1) v += __shfl_xor(v, m, 64);
    int w = threadIdx.x >> 6;
    __syncthreads();
    if ((threadIdx.x & 63) == 0) sb[w] = v;
    __syncthreads();
    return sb[0] + sb[1] + sb[2] + sb[3];
}
__device__ __forceinline__ float2 blk_sum2(float2 v, float* sb) {
#pragma unroll
    for (int m = 1; m < 64; m <<= 1) {
        v.x += __shfl_xor(v.x, m, 64);
        v.y += __shfl_xor(v.y, m, 64);
    }
    int w = threadIdx.x >> 6;
    __syncthreads();
    if ((threadIdx.x & 63) == 0) { sb[w * 2] = v.x; sb[w * 2 + 1] = v.y; }
    __syncthreads();
    return make_float2(sb[0] + sb[2] + sb[4] + sb[6], sb[1] + sb[3] + sb[5] + sb[7]);
}

// ---------------------------------------------------------------- gate + first LN (one row/block)
__global__ __launch_bounds__(256)
void gate_ln1_k(const float* __restrict__ qin, const bf16* __restrict__ xb,
                const float* __restrict__ gp0, const float* __restrict__ gp1,
                const float* __restrict__ gb1, const float* __restrict__ gw2,
                const float* __restrict__ gb2, const float* __restrict__ entm,
                const float* __restrict__ lng, const float* __restrict__ lnb,
                bf16* __restrict__ q2b) {
    __shared__ float sb[8];
    const int row = blockIdx.x, t = threadIdx.x, c0 = t * 4;
    float4 p0 = *(const float4*)(gp0 + (size_t)row * D_ + c0);
    float4 p1 = *(const float4*)(gp1 + (size_t)row * D_ + c0);
    float4 hb = *(const float4*)(gb1 + c0);
    float h0 = gelu_f(p0.x + p1.x + hb.x);
    float h1 = gelu_f(p0.y + p1.y + hb.y);
    float h2 = gelu_f(p0.z + p1.z + hb.z);
    float h3 = gelu_f(p0.w + p1.w + hb.w);
    float4 g4 = *(const float4*)(gw2 + c0);
    float dot = h0 * g4.x + h1 * g4.y + h2 * g4.z + h3 * g4.w;
    dot = blk_sum(dot, sb);
    float g = 1.0f / (1.0f + expf(-(dot + gb2[0])));
    float conf = fminf(fmaxf(1.0f - entm[row], 0.0f), 1.0f);
    g *= conf;
    float4 qv = *(const float4*)(qin + (size_t)row * D_ + c0);
    bf16x4 a4 = *(const bf16x4*)(xb + (size_t)row * 2048 + 1024 + c0);
    float y[4] = { qv.x + (float)a4[0] * g, qv.y + (float)a4[1] * g,
                   qv.z + (float)a4[2] * g, qv.w + (float)a4[3] * g };
    float2 ss = blk_sum2(make_float2(y[0] + y[1] + y[2] + y[3],
                                     y[0]*y[0] + y[1]*y[1] + y[2]*y[2] + y[3]*y[3]), sb);
    float mu = ss.x * (1.0f / D_);
    float var = ss.y * (1.0f / D_) - mu * mu;
    float rs = rsqrtf(var + 1e-5f);
    float4 gg = *(const float4*)(lng + c0);
    float4 bb = *(const float4*)(lnb + c0);
    bf16x4 ob;
    ob[0] = (bf16)((y[0] - mu) * rs * gg.x + bb.x);
    ob[1] = (bf16)((y[1] - mu) * rs * gg.y + bb.y);
    ob[2] = (bf16)((y[2] - mu) * rs * gg.z + bb.z);
    ob[3] = (bf16)((y[3] - mu) * rs * gg.w + bb.w);
    *(bf16x4*)(q2b + (size_t)row * D_ + c0) = ob;
}

// ---------------------------------------------------------------- residual(bf16) + ffn partials + LN -> out
__global__ __launch_bounds__(256)
void ln2_k(const bf16* __restrict__ q2b, const float* __restrict__ fp0,
           const float* __restrict__ fp1, const float* __restrict__ b2,
           const float* __restrict__ lng, const float* __restrict__ lnb,
           float* __restrict__ outp) {
    __shared__ float sb[8];
    const int row = blockIdx.x, t = threadIdx.x, c0 = t * 4;
    bf16x4 a4 = *(const bf16x4*)(q2b + (size_t)row * D_ + c0);
    float4 f0 = *(const float4*)(fp0 + (size_t)row * D_ + c0);
    float4 f1 = *(const float4*)(fp1 + (size_t)row * D_ + c0);
    float4 bv = *(const float4*)(b2 + c0);
    float y[4] = { (float)a4[0] + f0.x + f1.x + bv.x, (float)a4[1] + f0.y + f1.y + bv.y,
                   (float)a4[2] + f0.z + f1.z + bv.z, (float)a4[3] + f0.w + f1.w + bv.w };
    float2 ss = blk_sum2(make_float2(y[0] + y[1] + y[2] + y[3],
                                     y[0]*y[0] + y[1]*y[1] + y[2]*y[2] + y[3]*y[3]), sb);
    float mu = ss.x * (1.0f / D_);
    float var = ss.y * (1.0f / D_) - mu * mu;
    float rs = rsqrtf(var + 1e-5f);
    float4 gg = *(const float4*)(lng + c0);
    float4 bb = *(const float4*)(lnb + c0);
    *(float4*)(outp + (size_t)row * D_ + c0) = make_float4(
        (y[0] - mu) * rs * gg.x + bb.x, (y[1] - mu) * rs * gg.y + bb.y,
        (y[2] - mu) * rs * gg.z + bb.z, (y[3] - mu) * rs * gg.w + bb.w);
}

// ---------------------------------------------------------------- launch
extern "C" void kernel_launch(void* const* d_in, const int* in_sizes, int n_in,
                              void* d_out, int out_size, void* d_ws, size_t ws_size,
                              hipStream_t stream) {
    (void)in_sizes; (void)n_in; (void)out_size; (void)ws_size;
    const float* q    = (const float*)d_in[0];
    const float* kv   = (const float*)d_in[2];
    const float* ipw  = (const float*)d_in[4];
    const float* ipb  = (const float*)d_in[5];
    const float* outw = (const float*)d_in[6];
    const float* outb = (const float*)d_in[7];
    const float* lng  = (const float*)d_in[8];
    const float* lnb  = (const float*)d_in[9];
    const float* w1   = (const float*)d_in[10];
    const float* b1   = (const float*)d_in[11];
    const float* w2   = (const float*)d_in[12];
    const float* b2   = (const float*)d_in[13];
    const float* gw1  = (const float*)d_in[14];
    const float* gb1  = (const float*)d_in[15];
    const float* gw2  = (const float*)d_in[16];
    const float* gb2  = (const float*)d_in[17];

    char* ws = (char*)d_ws;
    const size_t MB = 1u << 20;
    bf16*  ipw_b  = (bf16*)(ws + 0);         // [0,6)
    bf16*  outw_b = (bf16*)(ws + 6 * MB);    // [6,8)
    bf16*  w1_b   = (bf16*)(ws + 8 * MB);    // [8,16)
    bf16*  w2_b   = (bf16*)(ws + 16 * MB);   // [16,24)
    bf16*  gw1_b  = (bf16*)(ws + 24 * MB);   // [24,28)
    bf16*  x_b    = (bf16*)(ws + 28 * MB);   // [28,44)  4096x2048 [q | attn_out]
    bf16*  kv_b   = (bf16*)(ws + 44 * MB);   // [44,60)
    bf16*  Qp     = (bf16*)(ws + 60 * MB);   // [60,68)
    bf16*  Kp     = (bf16*)(ws + 68 * MB);   // [68,84)  [8192][1024]
    bf16*  Vt     = (bf16*)(ws + 84 * MB);   // [84,100) [1024][8192] = V^T
    bf16*  ctx    = (bf16*)(ws + 100 * MB);  // [100,108)
    // reuse (lifetimes disjoint):
    float* gp0    = (float*)(ws + 44 * MB);  // [44,60)  over kv_b
    float* gp1    = (float*)(ws + 60 * MB);  // [60,76)  over Qp + Kp-head
    bf16*  q2b    = (bf16*)(ws + 100 * MB);  // [100,108) over ctx
    bf16*  h1     = (bf16*)(ws + 44 * MB);   // [44,76)  over gp0/gp1
    float* fp0    = (float*)(ws + 28 * MB);  // [28,44)  over x_b
    float* fp1    = (float*)(ws + 0);        // [0,16)   over ipw/outw/w1_b

    float* out  = (float*)d_out;
    float* entm = out + (size_t)MQ_ * D_;

    (void)hipMemsetAsync(entm, 0, (size_t)MQ_ * sizeof(float), stream);

    cast_all_k<<<13312, 256, 0, stream>>>(ipw, outw, w1, w2, gw1, q, kv,
                                          ipw_b, outw_b, w1_b, w2_b, gw1_b, x_b, kv_b);

    gemm_proj3_k<<<640, 512, 0, stream>>>(x_b, kv_b, ipw_b, ipb, Qp, Kp, Vt);
    attn_k<<<dim3(H_, B_, LQ_ / 64), 256, 0, stream>>>(Qp, Kp, Vt, ctx, entm);
    gemmP_outproj_k<<<dim3(8, 32), 256, 0, stream>>>(ctx, outw_b, outb, x_b + 1024);
    gemmP_gate2_k<<<dim3(8, 32, 2), 256, 0, stream>>>(x_b, gw1_b, gp0, gp1);
    gate_ln1_k<<<MQ_, 256, 0, stream>>>(q, x_b, gp0, gp1, gb1, gw2, gb2, entm, lng, lnb, q2b);
    gemmA_ffn1_k<<<dim3(16, 32), 512, 0, stream>>>(q2b, w1_b, b1, h1);
    gemmP_ffn2_k<<<dim3(8, 32, 2), 256, 0, stream>>>(h1, w2_b, fp0, fp1);
    ln2_k<<<MQ_, 256, 0, stream>>>(q2b, fp0, fp1, b2, lng, lnb, out);
}

// Round 14
// 276.909 us; speedup vs baseline: 1.1318x; 1.0199x over previous
//
#include <hip/hip_runtime.h>
#include <cstdint>
#include <cstddef>

typedef __bf16 bf16;
typedef __bf16 bf16x8 __attribute__((ext_vector_type(8)));
typedef __bf16 bf16x4 __attribute__((ext_vector_type(4)));
typedef float  f32x4  __attribute__((ext_vector_type(4)));

#define GLOAD_LDS16(g, l) __builtin_amdgcn_global_load_lds( \
    (const __attribute__((address_space(1))) unsigned int*)(g), \
    (__attribute__((address_space(3))) unsigned int*)(l), 16, 0, 0)

static constexpr int D_  = 1024;
static constexpr int H_  = 16;
static constexpr int HD_ = 64;
static constexpr int B_  = 8;
static constexpr int LQ_ = 512;
static constexpr int LK_ = 1024;
static constexpr int MQ_ = B_ * LQ_;   // 4096 query rows
static constexpr int MK_ = B_ * LK_;   // 8192 kv rows
static constexpr float LOG2E_ = 1.4426950408889634f;
static constexpr float INV_LN_LK_ = 0.14426950408889634f; // 1/ln(1024)
static constexpr float CSHIFT_ = 8.0f;                    // fixed softmax shift

// fast gelu (tanh form, folded to x*sigmoid(2z)); |err vs erf-gelu| <= ~1e-3
__device__ __forceinline__ float gelu_f(float v) {
    float v2 = v * v;
    float u = fmaf(0.035677408136f, v2, 0.7978845608028654f);
    float s = exp2f(v * u * -2.8853900817779268f);
    return v / (1.0f + s);
}

// ---------------------------------------------------------------- fused casts
__global__ __launch_bounds__(256)
void cast_all_k(const float* __restrict__ ipw, const float* __restrict__ outw,
                const float* __restrict__ w1,  const float* __restrict__ w2,
                const float* __restrict__ gw1, const float* __restrict__ q,
                const float* __restrict__ kv,
                bf16* __restrict__ ipw_b, bf16* __restrict__ outw_b,
                bf16* __restrict__ w1_b,  bf16* __restrict__ w2_b,
                bf16* __restrict__ gw1_b, bf16* __restrict__ x_b,
                bf16* __restrict__ kv_b) {
    const int b = blockIdx.x, t = threadIdx.x;
    const float* src; bf16* dst; long e;
    if (b < 1536)       { src = ipw;  dst = ipw_b;  e = (long)b * 2048; }
    else if (b < 2048)  { src = outw; dst = outw_b; e = (long)(b - 1536) * 2048; }
    else if (b < 4096)  { src = w1;   dst = w1_b;   e = (long)(b - 2048) * 2048; }
    else if (b < 6144)  { src = w2;   dst = w2_b;   e = (long)(b - 4096) * 2048; }
    else if (b < 7168)  { src = gw1;  dst = gw1_b;  e = (long)(b - 6144) * 2048; }
    else if (b < 11264) { src = kv;   dst = kv_b;   e = (long)(b - 7168) * 2048; }
    else {  // q: strided write into x_b left half (dld 2048)
        long e2 = (long)(b - 11264) * 2048 + t * 8;
        float4 a = *(const float4*)(q + e2);
        float4 c = *(const float4*)(q + e2 + 4);
        bf16x8 o;
        o[0]=(bf16)a.x; o[1]=(bf16)a.y; o[2]=(bf16)a.z; o[3]=(bf16)a.w;
        o[4]=(bf16)c.x; o[5]=(bf16)c.y; o[6]=(bf16)c.z; o[7]=(bf16)c.w;
        long row = e2 >> 10, col = e2 & 1023;
        *(bf16x8*)(x_b + row * 2048 + col) = o;
        return;
    }
    e += t * 8;
    float4 a = *(const float4*)(src + e);
    float4 c = *(const float4*)(src + e + 4);
    bf16x8 o;
    o[0]=(bf16)a.x; o[1]=(bf16)a.y; o[2]=(bf16)a.z; o[3]=(bf16)a.w;
    o[4]=(bf16)c.x; o[5]=(bf16)c.y; o[6]=(bf16)c.z; o[7]=(bf16)c.w;
    *(bf16x8*)(dst + e) = o;
}

// ---------------------------------------------------------------- 128x128 pipelined GEMM (gemmP)
// Depth-2 ring, counted vmcnt, swizzle both sides; bf16 output (split-K partials also bf16).
template<int SPLITK>
__device__ __forceinline__
void gemmP_body(const bf16* __restrict__ A, int lda,
                const bf16* __restrict__ W, int ldw,
                const float* __restrict__ bias,
                bf16* __restrict__ Cb0, bf16* __restrict__ Cb1, int ldcb,
                int K, int aoff, int woff) {
    __shared__ __attribute__((aligned(16))) bf16 LDSp[3 * 8192];
    const int gx = gridDim.x, gy = gridDim.y;
    const int nwg = gx * gy * gridDim.z;
    const int flat = blockIdx.x + gx * (blockIdx.y + gy * blockIdx.z);
    const int swz = (flat & 7) * (nwg >> 3) + (flat >> 3);
    int rem = swz, z = 0;
    if (SPLITK) { z = swz / (gx * gy); rem = swz - z * (gx * gy); }
    const int by = rem / gx, bx = rem - by * gx;
    if (SPLITK) { A += (size_t)z * aoff; W += (size_t)z * woff; }
    bf16* Cb = (SPLITK && z) ? Cb1 : Cb0;

    const int t = threadIdx.x;
    const int w = t >> 6, l = t & 63, l15 = l & 15, lg = l >> 4;
    const int row0 = by * 128, col0 = bx * 128;
    const int wr = (w >> 1) * 64, wc = (w & 1) * 64;

    const int sr = t >> 2;
    const int sc = ((t & 3) ^ ((sr >> 1) & 3)) << 3;
    const bf16* pA0 = A + (size_t)(row0 + sr) * lda + sc;
    const bf16* pA1 = A + (size_t)(row0 + 64 + sr) * lda + sc;
    const bf16* pW0 = W + (size_t)(col0 + sr) * ldw + sc;
    const bf16* pW1 = W + (size_t)(col0 + 64 + sr) * ldw + sc;
    const int lo0 = w * 512, lo1 = 2048 + w * 512;

    auto STAGE = [&](int kt, int slot) {
        bf16* base = (bf16*)LDSp + slot * 8192;
        const int kc = kt * 32;
        GLOAD_LDS16(pA0 + kc, base + lo0);
        GLOAD_LDS16(pA1 + kc, base + lo1);
        GLOAD_LDS16(pW0 + kc, base + 4096 + lo0);
        GLOAD_LDS16(pW1 + kc, base + 4096 + lo1);
    };

    f32x4 acc[4][4];
#pragma unroll
    for (int m = 0; m < 4; ++m)
#pragma unroll
        for (int n = 0; n < 4; ++n) acc[m][n] = f32x4{0.f, 0.f, 0.f, 0.f};

    const int nk = K >> 5;
    STAGE(0, 0); STAGE(1, 1);
    asm volatile("s_waitcnt vmcnt(4)" ::: "memory");
    __builtin_amdgcn_s_barrier();

    int s0 = 0, s1 = 1, s2 = 2;
    const int kcol = (lg ^ ((l15 >> 1) & 3)) << 3;
    for (int kt = 0; kt < nk; ++kt) {
        const bf16* bufA = (const bf16*)LDSp + s0 * 8192;
        const bf16* bufB = bufA + 4096;
        bf16x8 af[4], bf4[4];
#pragma unroll
        for (int m = 0; m < 4; ++m)
            af[m] = *(const bf16x8*)&bufA[(wr + m * 16 + l15) * 32 + kcol];
#pragma unroll
        for (int n = 0; n < 4; ++n)
            bf4[n] = *(const bf16x8*)&bufB[(wc + n * 16 + l15) * 32 + kcol];
        if (kt + 2 < nk) STAGE(kt + 2, s2);
        __builtin_amdgcn_s_setprio(1);
#pragma unroll
        for (int m = 0; m < 4; ++m)
#pragma unroll
            for (int n = 0; n < 4; ++n)
                acc[m][n] = __builtin_amdgcn_mfma_f32_16x16x32_bf16(af[m], bf4[n], acc[m][n], 0, 0, 0);
        __builtin_amdgcn_s_setprio(0);
        asm volatile("s_waitcnt lgkmcnt(0)" ::: "memory");
        __builtin_amdgcn_sched_barrier(0);
        if (kt + 2 < nk) {
            asm volatile("s_waitcnt vmcnt(4)" ::: "memory");
        } else {
            asm volatile("s_waitcnt vmcnt(0)" ::: "memory");
        }
        __builtin_amdgcn_s_barrier();
        const int tmp = s0; s0 = s1; s1 = s2; s2 = tmp;
    }

    // repack epilogue (bias=nullptr for split-K partials)
    float bvn[4];
#pragma unroll
    for (int n = 0; n < 4; ++n) bvn[n] = bias ? bias[col0 + wc + n * 16 + l15] : 0.f;
    const int erow = l >> 2, ec = (l & 3) * 16;
#pragma unroll
    for (int m = 0; m < 4; ++m) {
        bf16* ep = (bf16*)LDSp + ((m & 1) * 4 + w) * 1152;
#pragma unroll
        for (int n = 0; n < 4; ++n)
#pragma unroll
            for (int r = 0; r < 4; ++r)
                ep[(lg * 4 + r) * 72 + n * 16 + l15] = (bf16)(acc[m][n][r] + bvn[n]);
        asm volatile("s_waitcnt lgkmcnt(0)" ::: "memory");
        __builtin_amdgcn_sched_barrier(0);
        bf16x8 v8a = *(const bf16x8*)&ep[erow * 72 + ec];
        bf16x8 v8b = *(const bf16x8*)&ep[erow * 72 + ec + 8];
        const int grow = row0 + wr + m * 16 + erow;
        bf16* dst = Cb + (size_t)grow * ldcb + col0 + wc + ec;
        *(bf16x8*)dst = v8a;
        *(bf16x8*)(dst + 8) = v8b;
    }
}

__global__ __launch_bounds__(256, 2)
void gemmP_outproj_k(const bf16* A, const bf16* W, const float* bias, bf16* Cb) {
    gemmP_body<0>(A, 1024, W, 1024, bias, Cb, nullptr, 2048, 1024, 0, 0);
}
__global__ __launch_bounds__(256, 2)
void gemmP_gate2_k(const bf16* A, const bf16* W, bf16* C0, bf16* C1) {
    gemmP_body<1>(A, 2048, W, 2048, nullptr, C0, C1, 1024, 1024, 1024, 1024);
}
__global__ __launch_bounds__(256, 2)
void gemmP_ffn2_k(const bf16* A, const bf16* W, bf16* C0, bf16* C1) {
    gemmP_body<1>(A, 4096, W, 4096, nullptr, C0, C1, 1024, 2048, 2048, 2048);
}

// ---------------------------------------------------------------- 128x256 GEMM body (LDS passed in)
template<int ACT, int ROWBIAS>
__device__ __forceinline__
void gemm128x256_body(bf16* LDSb, int by, int bx,
                      const bf16* __restrict__ A, int lda,
                      const bf16* __restrict__ W, int ldw,
                      const float* __restrict__ bias,
                      bf16* __restrict__ Cb, int ldcb, int K) {
    const int t = threadIdx.x;
    const int w = t >> 6, l = t & 63, l15 = l & 15, lg = l >> 4;
    const int wrr = w >> 2, wc = w & 3;
    const int row0 = by * 128, col0 = bx * 256;

    const int trow = t >> 2;
    const int scol = ((t & 3) ^ ((trow >> 1) & 3)) << 3;
    const bf16* pA  = A + (size_t)(row0 + trow) * lda + scol;
    const bf16* pB0 = W + (size_t)(col0 + trow) * ldw + scol;
    const bf16* pB1 = W + (size_t)(col0 + 128 + trow) * ldw + scol;
    const int ldsoA  = w * 512;
    const int ldsoB0 = 4096 + w * 512;
    const int ldsoB1 = 8192 + w * 512;

    f32x4 acc[4][4];
#pragma unroll
    for (int m = 0; m < 4; ++m)
#pragma unroll
        for (int n = 0; n < 4; ++n) acc[m][n] = f32x4{0.f, 0.f, 0.f, 0.f};

    const int nk = K >> 5;
    GLOAD_LDS16(pA,  LDSb + ldsoA);
    GLOAD_LDS16(pB0, LDSb + ldsoB0);
    GLOAD_LDS16(pB1, LDSb + ldsoB1);

    for (int kt = 0; kt < nk; ++kt) {
        const int cur = kt & 1;
        if (kt + 1 < nk) {
            const int kc = (kt + 1) * 32;
            bf16* d = LDSb + (cur ^ 1) * 12288;
            GLOAD_LDS16(pA + kc,  d + ldsoA);
            GLOAD_LDS16(pB0 + kc, d + ldsoB0);
            GLOAD_LDS16(pB1 + kc, d + ldsoB1);
            asm volatile("s_waitcnt vmcnt(3)" ::: "memory");
        } else {
            asm volatile("s_waitcnt vmcnt(0)" ::: "memory");
        }
        __builtin_amdgcn_s_barrier();
        const bf16* bufA = LDSb + cur * 12288;
        const bf16* bufB = bufA + 4096;
        const int kcol = (lg ^ ((l15 >> 1) & 3)) << 3;
        bf16x8 bf4[4];
#pragma unroll
        for (int n = 0; n < 4; ++n)
            bf4[n] = *(const bf16x8*)&bufB[(wc * 64 + n * 16 + l15) * 32 + kcol];
#pragma unroll
        for (int m = 0; m < 4; ++m) {
            bf16x8 afm = *(const bf16x8*)&bufA[(wrr * 64 + m * 16 + l15) * 32 + kcol];
#pragma unroll
            for (int n = 0; n < 4; ++n)
                acc[m][n] = __builtin_amdgcn_mfma_f32_16x16x32_bf16(afm, bf4[n], acc[m][n], 0, 0, 0);
        }
        asm volatile("s_waitcnt lgkmcnt(0)" ::: "memory");
        __builtin_amdgcn_sched_barrier(0);
        __builtin_amdgcn_s_barrier();
    }

    const int erow = l >> 2, ec = (l & 3) * 16;
    float bvn[4];
    if (!ROWBIAS) {
#pragma unroll
        for (int n = 0; n < 4; ++n) bvn[n] = bias[col0 + wc * 64 + n * 16 + l15];
    }
#pragma unroll
    for (int m = 0; m < 4; ++m) {
        float bvr[4];
        if (ROWBIAS) {
#pragma unroll
            for (int r = 0; r < 4; ++r)
                bvr[r] = bias[row0 + wrr * 64 + m * 16 + lg * 4 + r];
        }
        bf16* ep = LDSb + ((m & 1) * 8 + w) * 1152;
#pragma unroll
        for (int n = 0; n < 4; ++n)
#pragma unroll
            for (int r = 0; r < 4; ++r) {
                float v = acc[m][n][r] + (ROWBIAS ? bvr[r] : bvn[n]);
                if (ACT) v = gelu_f(v);
                ep[(lg * 4 + r) * 72 + n * 16 + l15] = (bf16)v;
            }
        asm volatile("s_waitcnt lgkmcnt(0)" ::: "memory");
        __builtin_amdgcn_sched_barrier(0);
        bf16x8 v8a = *(const bf16x8*)&ep[erow * 72 + ec];
        bf16x8 v8b = *(const bf16x8*)&ep[erow * 72 + ec + 8];
        const int grow = row0 + wrr * 64 + m * 16 + erow;
        bf16* dst = Cb + (size_t)grow * ldcb + col0 + wc * 64 + ec;
        *(bf16x8*)dst = v8a;
        *(bf16x8*)(dst + 8) = v8b;
    }
}

// merged q/k/vT projections: [0,256) kproj | [256,512) vprojT | [512,640) qproj.
// XCD x covers kv rows [1024x,1024(x+1)) for BOTH kproj (via by) and vprojT (via bx) -> shared L2 panel.
__global__ __launch_bounds__(512, 4)
void gemm_proj3_k(const bf16* __restrict__ xb, const bf16* __restrict__ kvb,
                  const bf16* __restrict__ ipw_b, const float* __restrict__ ipb,
                  bf16* __restrict__ Qp, bf16* __restrict__ Kp, bf16* __restrict__ Vt) {
    __shared__ __attribute__((aligned(16))) bf16 LDSb[2 * 12288];
    const int fb = blockIdx.x;
    if (fb < 256) {              // kproj: M=8192 N=1024 -> grid 64(by) x 4(bx)
        const int id = fb;
        const int swz = (id & 7) * 32 + (id >> 3);
        gemm128x256_body<0, 0>(LDSb, swz >> 2, swz & 3, kvb, 1024, ipw_b + 1024 * 1024, 1024,
                               ipb + 1024, Kp, 1024, 1024);
    } else if (fb < 512) {       // vprojT: M=1024 N=8192 (row bias) -> grid 8(by) x 32(bx)
        const int id = fb - 256;
        const int bx = (id & 7) * 4 + ((id >> 3) & 3);   // kv-row panel XCD-aligned
        const int by = id >> 5;
        gemm128x256_body<0, 1>(LDSb, by, bx, ipw_b + 2048 * 1024, 1024, kvb, 1024,
                               ipb + 2048, Vt, 8192, 1024);
    } else {                     // qproj: M=4096 N=1024 -> grid 32(by) x 4(bx)
        const int id = fb - 512; // 0..127
        const int swz = (id & 7) * 16 + (id >> 3);
        gemm128x256_body<0, 0>(LDSb, swz >> 2, swz & 3, xb, 2048, ipw_b, 1024, ipb, Qp, 1024, 1024);
    }
}

__global__ __launch_bounds__(512, 4)
void gemmA_ffn1_k(const bf16* A, const bf16* W, const float* bias, bf16* Cb) {
    __shared__ __attribute__((aligned(16))) bf16 LDSb[2 * 12288];
    // 2D-region XCD swizzle: 8 regions of 8(by) x 8(bx); grid 32x16
    const int f = blockIdx.x + gridDim.x * blockIdx.y;
    const int x = f & 7, i = f >> 3;
    const int by = (x >> 1) * 8 + (i >> 3);
    const int bx = (x & 1) * 8 + (i & 7);
    gemm128x256_body<1, 0>(LDSb, by, bx, A, 1024, W, 1024, bias, Cb, 4096, 1024);
}

// ---------------------------------------------------------------- flash attention + entropy
__device__ __forceinline__ float red16sum(float v) {
    v += __shfl_xor(v, 1, 64);
    v += __shfl_xor(v, 2, 64);
    v += __shfl_xor(v, 4, 64);
    v += __shfl_xor(v, 8, 64);
    return v;
}

__global__ __launch_bounds__(256)
void attn_k(const bf16* __restrict__ Qp, const bf16* __restrict__ Kp,
            const bf16* __restrict__ Vt, bf16* __restrict__ ctx,
            float* __restrict__ entm) {
    __shared__ __attribute__((aligned(16))) bf16 Ks[64 * 64];
    __shared__ __attribute__((aligned(16))) bf16 Vs[64 * 64];
    __shared__ __attribute__((aligned(16))) bf16 Ps[4][16 * 72];
    const int t = threadIdx.x, w = t >> 6, l = t & 63;
    const int l15 = l & 15, lg = l >> 4;
    const int h = blockIdx.x, b = blockIdx.y, qt = blockIdx.z;
    const int qrow0 = b * LQ_ + qt * 64 + w * 16;

    bf16x8 aq[2];
#pragma unroll
    for (int kk = 0; kk < 2; ++kk)
        aq[kk] = *(const bf16x8*)(Qp + (size_t)(qrow0 + l15) * D_ + h * HD_ + kk * 32 + lg * 8);

    const int r0 = t >> 3, r1 = 32 + (t >> 3), j = t & 7;
    const bf16* pK0 = Kp + (size_t)(b * LK_ + r0) * 1024 + h * HD_ + ((j ^ (r0 & 7)) << 3);
    const bf16* pK1 = Kp + (size_t)(b * LK_ + r1) * 1024 + h * HD_ + ((j ^ (r1 & 7)) << 3);
    const bf16* pV0 = Vt + (size_t)(h * HD_ + r0) * (size_t)MK_ + b * LK_ + ((j ^ (r0 & 7)) << 3);
    const bf16* pV1 = Vt + (size_t)(h * HD_ + r1) * (size_t)MK_ + b * LK_ + ((j ^ (r1 & 7)) << 3);
    const int ldsoL = w * 512, ldsoH = 2048 + w * 512;

    auto STAGE = [&](int c) {
        const size_t kadv = (size_t)c * 64 * 1024;
        const size_t vadv = (size_t)c * 64;
        GLOAD_LDS16(pK0 + kadv, (bf16*)Ks + ldsoL);
        GLOAD_LDS16(pK1 + kadv, (bf16*)Ks + ldsoH);
        GLOAD_LDS16(pV0 + vadv, (bf16*)Vs + ldsoL);
        GLOAD_LDS16(pV1 + vadv, (bf16*)Vs + ldsoH);
    };

    f32x4 o[4];
    float Zp[4], S1p[4];
#pragma unroll
    for (int n = 0; n < 4; ++n) o[n] = f32x4{0.f, 0.f, 0.f, 0.f};
#pragma unroll
    for (int r = 0; r < 4; ++r) { Zp[r] = 0.f; S1p[r] = 0.f; }

    const float K1 = 0.125f * LOG2E_;
    const float K0 = -CSHIFT_ * LOG2E_;
    const int swk = l15 & 7;

    for (int c = 0; c < LK_ / 64; ++c) {
        STAGE(c);
        asm volatile("s_waitcnt vmcnt(0)" ::: "memory");
        __builtin_amdgcn_s_barrier();

        f32x4 s[4];
#pragma unroll
        for (int n = 0; n < 4; ++n) {
            s[n] = f32x4{0.f, 0.f, 0.f, 0.f};
#pragma unroll
            for (int kk = 0; kk < 2; ++kk) {
                bf16x8 bk = *(const bf16x8*)&Ks[(n * 16 + l15) * 64 + ((((kk << 2) | lg) ^ swk) << 3)];
                s[n] = __builtin_amdgcn_mfma_f32_16x16x32_bf16(aq[kk], bk, s[n], 0, 0, 0);
            }
        }

        float p[4][4];
#pragma unroll
        for (int r = 0; r < 4; ++r) {
#pragma unroll
            for (int n = 0; n < 4; ++n) {
                float sv = s[n][r];
                float pv = exp2f(fmaf(sv, K1, K0));
                p[n][r] = pv;
                Zp[r] += pv;
                S1p[r] = fmaf(pv, sv, S1p[r]);
            }
        }

#pragma unroll
        for (int r = 0; r < 4; ++r)
#pragma unroll
            for (int n = 0; n < 4; ++n)
                Ps[w][(lg * 4 + r) * 72 + ((n ^ lg) << 4) + l15] = (bf16)p[n][r];

        bf16x8 ap[2];
#pragma unroll
        for (int kk = 0; kk < 2; ++kk)
            ap[kk] = *(const bf16x8*)&Ps[w][l15 * 72 + ((kk * 32 + lg * 8) ^ (((l15 >> 2) & 3) << 4))];
#pragma unroll
        for (int n = 0; n < 4; ++n)
#pragma unroll
            for (int kk = 0; kk < 2; ++kk) {
                bf16x8 bv = *(const bf16x8*)&Vs[(n * 16 + l15) * 64 + ((((kk << 2) | lg) ^ swk) << 3)];
                o[n] = __builtin_amdgcn_mfma_f32_16x16x32_bf16(ap[kk], bv, o[n], 0, 0, 0);
            }

        asm volatile("s_waitcnt lgkmcnt(0)" ::: "memory");
        __builtin_amdgcn_sched_barrier(0);
        __builtin_amdgcn_s_barrier();
    }

#pragma unroll
    for (int r = 0; r < 4; ++r) {
        float Zr = red16sum(Zp[r]);
        float S1r = red16sum(S1p[r]) * 0.125f;
        float inv = 1.0f / Zr;
        int grow = qrow0 + lg * 4 + r;
#pragma unroll
        for (int n = 0; n < 4; ++n)
            ctx[(size_t)grow * D_ + h * HD_ + n * 16 + l15] = (bf16)(o[n][r] * inv);
        if (l15 == 0) {
            float ent = (CSHIFT_ + logf(Zr) - S1r * inv) * INV_LN_LK_ * (1.0f / 16.0f);
            atomicAdd(&entm[grow], ent);
        }
    }
}

// ---------------------------------------------------------------- block reductions
__device__ __forceinline__ float blk_sum(float v, float* sb) {
#pragma unroll
    for (int m = 1; m < 64; m <<= 1) v += __shfl_xor(v, m, 64);
    int w = threadIdx.x >> 6;
    __syncthreads();
    if ((threadIdx.x & 63) == 0) sb[w] = v;
    __syncthreads();
    return sb[0] + sb[1] + sb[2] + sb[3];
}
__device__ __forceinline__ float2 blk_sum2(float2 v, float* sb) {
#pragma unroll
    for (int m = 1; m < 64; m <<= 1) {
        v.x += __shfl_xor(v.x, m, 64);
        v.y += __shfl_xor(v.y, m, 64);
    }
    int w = threadIdx.x >> 6;
    __syncthreads();
    if ((threadIdx.x & 63) == 0) { sb[w * 2] = v.x; sb[w * 2 + 1] = v.y; }
    __syncthreads();
    return make_float2(sb[0] + sb[2] + sb[4] + sb[6], sb[1] + sb[3] + sb[5] + sb[7]);
}

// ---------------------------------------------------------------- gate + first LN (one row/block)
__global__ __launch_bounds__(256)
void gate_ln1_k(const float* __restrict__ qin, const bf16* __restrict__ xb,
                const bf16* __restrict__ gp0, const bf16* __restrict__ gp1,
                const float* __restrict__ gb1, const float* __restrict__ gw2,
                const float* __restrict__ gb2, const float* __restrict__ entm,
                const float* __restrict__ lng, const float* __restrict__ lnb,
                bf16* __restrict__ q2b) {
    __shared__ float sb[8];
    const int row = blockIdx.x, t = threadIdx.x, c0 = t * 4;
    bf16x4 pa = *(const bf16x4*)(gp0 + (size_t)row * D_ + c0);
    bf16x4 pb = *(const bf16x4*)(gp1 + (size_t)row * D_ + c0);
    float4 hb = *(const float4*)(gb1 + c0);
    float h0 = gelu_f((float)pa[0] + (float)pb[0] + hb.x);
    float h1 = gelu_f((float)pa[1] + (float)pb[1] + hb.y);
    float h2 = gelu_f((float)pa[2] + (float)pb[2] + hb.z);
    float h3 = gelu_f((float)pa[3] + (float)pb[3] + hb.w);
    float4 g4 = *(const float4*)(gw2 + c0);
    float dot = h0 * g4.x + h1 * g4.y + h2 * g4.z + h3 * g4.w;
    dot = blk_sum(dot, sb);
    float g = 1.0f / (1.0f + expf(-(dot + gb2[0])));
    float conf = fminf(fmaxf(1.0f - entm[row], 0.0f), 1.0f);
    g *= conf;
    float4 qv = *(const float4*)(qin + (size_t)row * D_ + c0);
    bf16x4 a4 = *(const bf16x4*)(xb + (size_t)row * 2048 + 1024 + c0);
    float y[4] = { qv.x + (float)a4[0] * g, qv.y + (float)a4[1] * g,
                   qv.z + (float)a4[2] * g, qv.w + (float)a4[3] * g };
    float2 ss = blk_sum2(make_float2(y[0] + y[1] + y[2] + y[3],
                                     y[0]*y[0] + y[1]*y[1] + y[2]*y[2] + y[3]*y[3]), sb);
    float mu = ss.x * (1.0f / D_);
    float var = ss.y * (1.0f / D_) - mu * mu;
    float rs = rsqrtf(var + 1e-5f);
    float4 gg = *(const float4*)(lng + c0);
    float4 bb = *(const float4*)(lnb + c0);
    bf16x4 ob;
    ob[0] = (bf16)((y[0] - mu) * rs * gg.x + bb.x);
    ob[1] = (bf16)((y[1] - mu) * rs * gg.y + bb.y);
    ob[2] = (bf16)((y[2] - mu) * rs * gg.z + bb.z);
    ob[3] = (bf16)((y[3] - mu) * rs * gg.w + bb.w);
    *(bf16x4*)(q2b + (size_t)row * D_ + c0) = ob;
}

// ---------------------------------------------------------------- residual(bf16) + ffn bf16 partials + LN -> out
__global__ __launch_bounds__(256)
void ln2_k(const bf16* __restrict__ q2b, const bf16* __restrict__ fp0,
           const bf16* __restrict__ fp1, const float* __restrict__ b2,
           const float* __restrict__ lng, const float* __restrict__ lnb,
           float* __restrict__ outp) {
    __shared__ float sb[8];
    const int row = blockIdx.x, t = threadIdx.x, c0 = t * 4;
    bf16x4 a4 = *(const bf16x4*)(q2b + (size_t)row * D_ + c0);
    bf16x4 f0 = *(const bf16x4*)(fp0 + (size_t)row * D_ + c0);
    bf16x4 f1 = *(const bf16x4*)(fp1 + (size_t)row * D_ + c0);
    float4 bv = *(const float4*)(b2 + c0);
    float y[4] = { (float)a4[0] + (float)f0[0] + (float)f1[0] + bv.x,
                   (float)a4[1] + (float)f0[1] + (float)f1[1] + bv.y,
                   (float)a4[2] + (float)f0[2] + (float)f1[2] + bv.z,
                   (float)a4[3] + (float)f0[3] + (float)f1[3] + bv.w };
    float2 ss = blk_sum2(make_float2(y[0] + y[1] + y[2] + y[3],
                                     y[0]*y[0] + y[1]*y[1] + y[2]*y[2] + y[3]*y[3]), sb);
    float mu = ss.x * (1.0f / D_);
    float var = ss.y * (1.0f / D_) - mu * mu;
    float rs = rsqrtf(var + 1e-5f);
    float4 gg = *(const float4*)(lng + c0);
    float4 bb = *(const float4*)(lnb + c0);
    *(float4*)(outp + (size_t)row * D_ + c0) = make_float4(
        (y[0] - mu) * rs * gg.x + bb.x, (y[1] - mu) * rs * gg.y + bb.y,
        (y[2] - mu) * rs * gg.z + bb.z, (y[3] - mu) * rs * gg.w + bb.w);
}

// ---------------------------------------------------------------- launch
extern "C" void kernel_launch(void* const* d_in, const int* in_sizes, int n_in,
                              void* d_out, int out_size, void* d_ws, size_t ws_size,
                              hipStream_t stream) {
    (void)in_sizes; (void)n_in; (void)out_size; (void)ws_size;
    const float* q    = (const float*)d_in[0];
    const float* kv   = (const float*)d_in[2];
    const float* ipw  = (const float*)d_in[4];
    const float* ipb  = (const float*)d_in[5];
    const float* outw = (const float*)d_in[6];
    const float* outb = (const float*)d_in[7];
    const float* lng  = (const float*)d_in[8];
    const float* lnb  = (const float*)d_in[9];
    const float* w1   = (const float*)d_in[10];
    const float* b1   = (const float*)d_in[11];
    const float* w2   = (const float*)d_in[12];
    const float* b2   = (const float*)d_in[13];
    const float* gw1  = (const float*)d_in[14];
    const float* gb1  = (const float*)d_in[15];
    const float* gw2  = (const float*)d_in[16];
    const float* gb2  = (const float*)d_in[17];

    char* ws = (char*)d_ws;
    const size_t MB = 1u << 20;
    bf16*  ipw_b  = (bf16*)(ws + 0);         // [0,6)
    bf16*  outw_b = (bf16*)(ws + 6 * MB);    // [6,8)
    bf16*  w1_b   = (bf16*)(ws + 8 * MB);    // [8,16)
    bf16*  w2_b   = (bf16*)(ws + 16 * MB);   // [16,24)
    bf16*  gw1_b  = (bf16*)(ws + 24 * MB);   // [24,28)
    bf16*  x_b    = (bf16*)(ws + 28 * MB);   // [28,44)  4096x2048 [q | attn_out]
    bf16*  kv_b   = (bf16*)(ws + 44 * MB);   // [44,60)
    bf16*  Qp     = (bf16*)(ws + 60 * MB);   // [60,68)
    bf16*  Kp     = (bf16*)(ws + 68 * MB);   // [68,84)  [8192][1024]
    bf16*  Vt     = (bf16*)(ws + 84 * MB);   // [84,100) [1024][8192] = V^T
    bf16*  ctx    = (bf16*)(ws + 100 * MB);  // [100,108)
    // reuse (lifetimes disjoint):
    bf16*  gp0    = (bf16*)(ws + 44 * MB);   // [44,52)  over kv_b (dead after proj3)
    bf16*  gp1    = (bf16*)(ws + 52 * MB);   // [52,60)
    bf16*  q2b    = (bf16*)(ws + 100 * MB);  // [100,108) over ctx (dead after outproj)
    bf16*  h1     = (bf16*)(ws + 44 * MB);   // [44,76)  over gp0/gp1 (dead after gate_ln1)
    bf16*  fp0    = (bf16*)(ws + 28 * MB);   // [28,36)  over x_b (dead after gate_ln1)
    bf16*  fp1    = (bf16*)(ws + 0);         // [0,8)    over ipw_b (dead)

    float* out  = (float*)d_out;
    float* entm = out + (size_t)MQ_ * D_;

    (void)hipMemsetAsync(entm, 0, (size_t)MQ_ * sizeof(float), stream);

    cast_all_k<<<13312, 256, 0, stream>>>(ipw, outw, w1, w2, gw1, q, kv,
                                          ipw_b, outw_b, w1_b, w2_b, gw1_b, x_b, kv_b);

    gemm_proj3_k<<<640, 512, 0, stream>>>(x_b, kv_b, ipw_b, ipb, Qp, Kp, Vt);
    attn_k<<<dim3(H_, B_, LQ_ / 64), 256, 0, stream>>>(Qp, Kp, Vt, ctx, entm);
    gemmP_outproj_k<<<dim3(8, 32), 256, 0, stream>>>(ctx, outw_b, outb, x_b + 1024);
    gemmP_gate2_k<<<dim3(8, 32, 2), 256, 0, stream>>>(x_b, gw1_b, gp0, gp1);
    gate_ln1_k<<<MQ_, 256, 0, stream>>>(q, x_b, gp0, gp1, gb1, gw2, gb2, entm, lng, lnb, q2b);
    gemmA_ffn1_k<<<dim3(16, 32), 512, 0, stream>>>(q2b, w1_b, b1, h1);
    gemmP_ffn2_k<<<dim3(8, 32, 2), 256, 0, stream>>>(h1, w2_b, fp0, fp1);
    ln2_k<<<MQ_, 256, 0, stream>>>(q2b, fp0, fp1, b2, lng, lnb, out);
}

// Round 15
// 275.833 us; speedup vs baseline: 1.1362x; 1.0039x over previous
//
#include <hip/hip_runtime.h>
#include <cstdint>
#include <cstddef>

typedef __bf16 bf16;
typedef __bf16 bf16x8 __attribute__((ext_vector_type(8)));
typedef __bf16 bf16x4 __attribute__((ext_vector_type(4)));
typedef float  f32x4  __attribute__((ext_vector_type(4)));

#define GLOAD_LDS16(g, l) __builtin_amdgcn_global_load_lds( \
    (const __attribute__((address_space(1))) unsigned int*)(g), \
    (__attribute__((address_space(3))) unsigned int*)(l), 16, 0, 0)

static constexpr int D_  = 1024;
static constexpr int H_  = 16;
static constexpr int HD_ = 64;
static constexpr int B_  = 8;
static constexpr int LQ_ = 512;
static constexpr int LK_ = 1024;
static constexpr int MQ_ = B_ * LQ_;   // 4096 query rows
static constexpr int MK_ = B_ * LK_;   // 8192 kv rows
static constexpr float LOG2E_ = 1.4426950408889634f;
static constexpr float INV_LN_LK_ = 0.14426950408889634f; // 1/ln(1024)
static constexpr float CSHIFT_ = 8.0f;                    // fixed softmax shift

// fast gelu (tanh form, folded to x*sigmoid(2z)); |err vs erf-gelu| <= ~1e-3
__device__ __forceinline__ float gelu_f(float v) {
    float v2 = v * v;
    float u = fmaf(0.035677408136f, v2, 0.7978845608028654f);
    float s = exp2f(v * u * -2.8853900817779268f);
    return v / (1.0f + s);
}

// ---------------------------------------------------------------- fused casts
__global__ __launch_bounds__(256)
void cast_all_k(const float* __restrict__ ipw, const float* __restrict__ outw,
                const float* __restrict__ w1,  const float* __restrict__ w2,
                const float* __restrict__ gw1, const float* __restrict__ q,
                const float* __restrict__ kv,
                bf16* __restrict__ ipw_b, bf16* __restrict__ outw_b,
                bf16* __restrict__ w1_b,  bf16* __restrict__ w2_b,
                bf16* __restrict__ gw1_b, bf16* __restrict__ x_b,
                bf16* __restrict__ kv_b) {
    const int b = blockIdx.x, t = threadIdx.x;
    const float* src; bf16* dst; long e;
    if (b < 1536)       { src = ipw;  dst = ipw_b;  e = (long)b * 2048; }
    else if (b < 2048)  { src = outw; dst = outw_b; e = (long)(b - 1536) * 2048; }
    else if (b < 4096)  { src = w1;   dst = w1_b;   e = (long)(b - 2048) * 2048; }
    else if (b < 6144)  { src = w2;   dst = w2_b;   e = (long)(b - 4096) * 2048; }
    else if (b < 7168)  { src = gw1;  dst = gw1_b;  e = (long)(b - 6144) * 2048; }
    else if (b < 11264) { src = kv;   dst = kv_b;   e = (long)(b - 7168) * 2048; }
    else {  // q: strided write into x_b left half (dld 2048)
        long e2 = (long)(b - 11264) * 2048 + t * 8;
        float4 a = *(const float4*)(q + e2);
        float4 c = *(const float4*)(q + e2 + 4);
        bf16x8 o;
        o[0]=(bf16)a.x; o[1]=(bf16)a.y; o[2]=(bf16)a.z; o[3]=(bf16)a.w;
        o[4]=(bf16)c.x; o[5]=(bf16)c.y; o[6]=(bf16)c.z; o[7]=(bf16)c.w;
        long row = e2 >> 10, col = e2 & 1023;
        *(bf16x8*)(x_b + row * 2048 + col) = o;
        return;
    }
    e += t * 8;
    float4 a = *(const float4*)(src + e);
    float4 c = *(const float4*)(src + e + 4);
    bf16x8 o;
    o[0]=(bf16)a.x; o[1]=(bf16)a.y; o[2]=(bf16)a.z; o[3]=(bf16)a.w;
    o[4]=(bf16)c.x; o[5]=(bf16)c.y; o[6]=(bf16)c.z; o[7]=(bf16)c.w;
    *(bf16x8*)(dst + e) = o;
}

// ---------------------------------------------------------------- 128x128 pipelined GEMM core (LDS passed in)
// Depth-2 ring, counted vmcnt, swizzle both sides; bf16 output via repack epilogue.
__device__ __forceinline__
void gemmP_core(bf16* LDSp, int by, int bx,
                const bf16* __restrict__ A, int lda,
                const bf16* __restrict__ W, int ldw,
                const float* __restrict__ bias,
                bf16* __restrict__ Cb, int ldcb, int K) {
    const int t = threadIdx.x;
    const int w = t >> 6, l = t & 63, l15 = l & 15, lg = l >> 4;
    const int row0 = by * 128, col0 = bx * 128;
    const int wr = (w >> 1) * 64, wc = (w & 1) * 64;

    const int sr = t >> 2;
    const int sc = ((t & 3) ^ ((sr >> 1) & 3)) << 3;
    const bf16* pA0 = A + (size_t)(row0 + sr) * lda + sc;
    const bf16* pA1 = A + (size_t)(row0 + 64 + sr) * lda + sc;
    const bf16* pW0 = W + (size_t)(col0 + sr) * ldw + sc;
    const bf16* pW1 = W + (size_t)(col0 + 64 + sr) * ldw + sc;
    const int lo0 = w * 512, lo1 = 2048 + w * 512;

    auto STAGE = [&](int kt, int slot) {
        bf16* base = LDSp + slot * 8192;
        const int kc = kt * 32;
        GLOAD_LDS16(pA0 + kc, base + lo0);
        GLOAD_LDS16(pA1 + kc, base + lo1);
        GLOAD_LDS16(pW0 + kc, base + 4096 + lo0);
        GLOAD_LDS16(pW1 + kc, base + 4096 + lo1);
    };

    f32x4 acc[4][4];
#pragma unroll
    for (int m = 0; m < 4; ++m)
#pragma unroll
        for (int n = 0; n < 4; ++n) acc[m][n] = f32x4{0.f, 0.f, 0.f, 0.f};

    const int nk = K >> 5;
    STAGE(0, 0); STAGE(1, 1);
    asm volatile("s_waitcnt vmcnt(4)" ::: "memory");
    __builtin_amdgcn_s_barrier();

    int s0 = 0, s1 = 1, s2 = 2;
    const int kcol = (lg ^ ((l15 >> 1) & 3)) << 3;
    for (int kt = 0; kt < nk; ++kt) {
        const bf16* bufA = LDSp + s0 * 8192;
        const bf16* bufB = bufA + 4096;
        bf16x8 af[4], bf4[4];
#pragma unroll
        for (int m = 0; m < 4; ++m)
            af[m] = *(const bf16x8*)&bufA[(wr + m * 16 + l15) * 32 + kcol];
#pragma unroll
        for (int n = 0; n < 4; ++n)
            bf4[n] = *(const bf16x8*)&bufB[(wc + n * 16 + l15) * 32 + kcol];
        if (kt + 2 < nk) STAGE(kt + 2, s2);
        __builtin_amdgcn_s_setprio(1);
#pragma unroll
        for (int m = 0; m < 4; ++m)
#pragma unroll
            for (int n = 0; n < 4; ++n)
                acc[m][n] = __builtin_amdgcn_mfma_f32_16x16x32_bf16(af[m], bf4[n], acc[m][n], 0, 0, 0);
        __builtin_amdgcn_s_setprio(0);
        asm volatile("s_waitcnt lgkmcnt(0)" ::: "memory");
        __builtin_amdgcn_sched_barrier(0);
        if (kt + 2 < nk) {
            asm volatile("s_waitcnt vmcnt(4)" ::: "memory");
        } else {
            asm volatile("s_waitcnt vmcnt(0)" ::: "memory");
        }
        __builtin_amdgcn_s_barrier();
        const int tmp = s0; s0 = s1; s1 = s2; s2 = tmp;
    }

    float bvn[4];
#pragma unroll
    for (int n = 0; n < 4; ++n) bvn[n] = bias ? bias[col0 + wc + n * 16 + l15] : 0.f;
    const int erow = l >> 2, ec = (l & 3) * 16;
#pragma unroll
    for (int m = 0; m < 4; ++m) {
        bf16* ep = LDSp + ((m & 1) * 4 + w) * 1152;
#pragma unroll
        for (int n = 0; n < 4; ++n)
#pragma unroll
            for (int r = 0; r < 4; ++r)
                ep[(lg * 4 + r) * 72 + n * 16 + l15] = (bf16)(acc[m][n][r] + bvn[n]);
        asm volatile("s_waitcnt lgkmcnt(0)" ::: "memory");
        __builtin_amdgcn_sched_barrier(0);
        bf16x8 v8a = *(const bf16x8*)&ep[erow * 72 + ec];
        bf16x8 v8b = *(const bf16x8*)&ep[erow * 72 + ec + 8];
        const int grow = row0 + wr + m * 16 + erow;
        bf16* dst = Cb + (size_t)grow * ldcb + col0 + wc + ec;
        *(bf16x8*)dst = v8a;
        *(bf16x8*)(dst + 8) = v8b;
    }
}

// merged outproj + gate-q (independent of attention output): 512 blocks @256t
__global__ __launch_bounds__(256, 2)
void gemm_opq_k(const bf16* __restrict__ ctx, const bf16* __restrict__ outw_b,
                const float* __restrict__ outb, const bf16* __restrict__ xb,
                const bf16* __restrict__ gw1_b, bf16* __restrict__ ao_out,
                bf16* __restrict__ gp0) {
    __shared__ __attribute__((aligned(16))) bf16 LDSp[3 * 8192];
    const int fb = blockIdx.x;
    const int id = fb & 255;
    const int swz = (id & 7) * 32 + (id >> 3);
    const int by = swz >> 3, bx = swz & 7;
    if (fb < 256)
        gemmP_core(LDSp, by, bx, ctx, 1024, outw_b, 1024, outb, ao_out, 2048, 1024);
    else
        gemmP_core(LDSp, by, bx, xb, 2048, gw1_b, 2048, nullptr, gp0, 1024, 1024);
}

// gate-k slice: ao @ gw1_right^T -> gp1 (256 blocks)
__global__ __launch_bounds__(256, 2)
void gemm_gatek_k(const bf16* __restrict__ xb, const bf16* __restrict__ gw1_b,
                  bf16* __restrict__ gp1) {
    __shared__ __attribute__((aligned(16))) bf16 LDSp[3 * 8192];
    const int id = blockIdx.x;
    const int swz = (id & 7) * 32 + (id >> 3);
    gemmP_core(LDSp, swz >> 3, swz & 7, xb + 1024, 2048, gw1_b + 1024, 2048,
               nullptr, gp1, 1024, 1024);
}

// ffn2 split-K=4: 1024 blocks, bf16 partials
__global__ __launch_bounds__(256, 2)
void gemm_ffn2_k(const bf16* __restrict__ h1, const bf16* __restrict__ w2_b,
                 bf16* __restrict__ f0, bf16* __restrict__ f1,
                 bf16* __restrict__ f2, bf16* __restrict__ f3) {
    __shared__ __attribute__((aligned(16))) bf16 LDSp[3 * 8192];
    const int flat = blockIdx.x;
    const int swz = (flat & 7) * 128 + (flat >> 3);
    const int z = swz >> 8, rem = swz & 255;
    bf16* Cb = (z == 0) ? f0 : (z == 1) ? f1 : (z == 2) ? f2 : f3;
    gemmP_core(LDSp, rem >> 3, rem & 7, h1 + z * 1024, 4096, w2_b + z * 1024, 4096,
               nullptr, Cb, 1024, 1024);
}

// ---------------------------------------------------------------- 128x256 GEMM body (LDS passed in)
template<int ACT, int ROWBIAS>
__device__ __forceinline__
void gemm128x256_body(bf16* LDSb, int by, int bx,
                      const bf16* __restrict__ A, int lda,
                      const bf16* __restrict__ W, int ldw,
                      const float* __restrict__ bias,
                      bf16* __restrict__ Cb, int ldcb, int K) {
    const int t = threadIdx.x;
    const int w = t >> 6, l = t & 63, l15 = l & 15, lg = l >> 4;
    const int wrr = w >> 2, wc = w & 3;
    const int row0 = by * 128, col0 = bx * 256;

    const int trow = t >> 2;
    const int scol = ((t & 3) ^ ((trow >> 1) & 3)) << 3;
    const bf16* pA  = A + (size_t)(row0 + trow) * lda + scol;
    const bf16* pB0 = W + (size_t)(col0 + trow) * ldw + scol;
    const bf16* pB1 = W + (size_t)(col0 + 128 + trow) * ldw + scol;
    const int ldsoA  = w * 512;
    const int ldsoB0 = 4096 + w * 512;
    const int ldsoB1 = 8192 + w * 512;

    f32x4 acc[4][4];
#pragma unroll
    for (int m = 0; m < 4; ++m)
#pragma unroll
        for (int n = 0; n < 4; ++n) acc[m][n] = f32x4{0.f, 0.f, 0.f, 0.f};

    const int nk = K >> 5;
    GLOAD_LDS16(pA,  LDSb + ldsoA);
    GLOAD_LDS16(pB0, LDSb + ldsoB0);
    GLOAD_LDS16(pB1, LDSb + ldsoB1);

    for (int kt = 0; kt < nk; ++kt) {
        const int cur = kt & 1;
        if (kt + 1 < nk) {
            const int kc = (kt + 1) * 32;
            bf16* d = LDSb + (cur ^ 1) * 12288;
            GLOAD_LDS16(pA + kc,  d + ldsoA);
            GLOAD_LDS16(pB0 + kc, d + ldsoB0);
            GLOAD_LDS16(pB1 + kc, d + ldsoB1);
            asm volatile("s_waitcnt vmcnt(3)" ::: "memory");
        } else {
            asm volatile("s_waitcnt vmcnt(0)" ::: "memory");
        }
        __builtin_amdgcn_s_barrier();
        const bf16* bufA = LDSb + cur * 12288;
        const bf16* bufB = bufA + 4096;
        const int kcol = (lg ^ ((l15 >> 1) & 3)) << 3;
        bf16x8 bf4[4];
#pragma unroll
        for (int n = 0; n < 4; ++n)
            bf4[n] = *(const bf16x8*)&bufB[(wc * 64 + n * 16 + l15) * 32 + kcol];
#pragma unroll
        for (int m = 0; m < 4; ++m) {
            bf16x8 afm = *(const bf16x8*)&bufA[(wrr * 64 + m * 16 + l15) * 32 + kcol];
#pragma unroll
            for (int n = 0; n < 4; ++n)
                acc[m][n] = __builtin_amdgcn_mfma_f32_16x16x32_bf16(afm, bf4[n], acc[m][n], 0, 0, 0);
        }
        asm volatile("s_waitcnt lgkmcnt(0)" ::: "memory");
        __builtin_amdgcn_sched_barrier(0);
        __builtin_amdgcn_s_barrier();
    }

    const int erow = l >> 2, ec = (l & 3) * 16;
    float bvn[4];
    if (!ROWBIAS) {
#pragma unroll
        for (int n = 0; n < 4; ++n) bvn[n] = bias[col0 + wc * 64 + n * 16 + l15];
    }
#pragma unroll
    for (int m = 0; m < 4; ++m) {
        float bvr[4];
        if (ROWBIAS) {
#pragma unroll
            for (int r = 0; r < 4; ++r)
                bvr[r] = bias[row0 + wrr * 64 + m * 16 + lg * 4 + r];
        }
        bf16* ep = LDSb + ((m & 1) * 8 + w) * 1152;
#pragma unroll
        for (int n = 0; n < 4; ++n)
#pragma unroll
            for (int r = 0; r < 4; ++r) {
                float v = acc[m][n][r] + (ROWBIAS ? bvr[r] : bvn[n]);
                if (ACT) v = gelu_f(v);
                ep[(lg * 4 + r) * 72 + n * 16 + l15] = (bf16)v;
            }
        asm volatile("s_waitcnt lgkmcnt(0)" ::: "memory");
        __builtin_amdgcn_sched_barrier(0);
        bf16x8 v8a = *(const bf16x8*)&ep[erow * 72 + ec];
        bf16x8 v8b = *(const bf16x8*)&ep[erow * 72 + ec + 8];
        const int grow = row0 + wrr * 64 + m * 16 + erow;
        bf16* dst = Cb + (size_t)grow * ldcb + col0 + wc * 64 + ec;
        *(bf16x8*)dst = v8a;
        *(bf16x8*)(dst + 8) = v8b;
    }
}

// merged q/k/vT projections: [0,256) kproj | [256,512) vprojT | [512,640) qproj.
__global__ __launch_bounds__(512, 4)
void gemm_proj3_k(const bf16* __restrict__ xb, const bf16* __restrict__ kvb,
                  const bf16* __restrict__ ipw_b, const float* __restrict__ ipb,
                  bf16* __restrict__ Qp, bf16* __restrict__ Kp, bf16* __restrict__ Vt) {
    __shared__ __attribute__((aligned(16))) bf16 LDSb[2 * 12288];
    const int fb = blockIdx.x;
    if (fb < 256) {              // kproj: M=8192 N=1024 -> grid 64(by) x 4(bx)
        const int id = fb;
        const int swz = (id & 7) * 32 + (id >> 3);
        gemm128x256_body<0, 0>(LDSb, swz >> 2, swz & 3, kvb, 1024, ipw_b + 1024 * 1024, 1024,
                               ipb + 1024, Kp, 1024, 1024);
    } else if (fb < 512) {       // vprojT: M=1024 N=8192 (row bias) -> V^T; kv-panel XCD-aligned
        const int id = fb - 256;
        const int bx = (id & 7) * 4 + ((id >> 3) & 3);
        const int by = id >> 5;
        gemm128x256_body<0, 1>(LDSb, by, bx, ipw_b + 2048 * 1024, 1024, kvb, 1024,
                               ipb + 2048, Vt, 8192, 1024);
    } else {                     // qproj: M=4096 N=1024 -> grid 32(by) x 4(bx)
        const int id = fb - 512;
        const int swz = (id & 7) * 16 + (id >> 3);
        gemm128x256_body<0, 0>(LDSb, swz >> 2, swz & 3, xb, 2048, ipw_b, 1024, ipb, Qp, 1024, 1024);
    }
}

__global__ __launch_bounds__(512, 4)
void gemmA_ffn1_k(const bf16* A, const bf16* W, const float* bias, bf16* Cb) {
    __shared__ __attribute__((aligned(16))) bf16 LDSb[2 * 12288];
    // 2D-region XCD swizzle: 8 regions of 8(by) x 8(bx); grid 32x16
    const int f = blockIdx.x + gridDim.x * blockIdx.y;
    const int x = f & 7, i = f >> 3;
    const int by = (x >> 1) * 8 + (i >> 3);
    const int bx = (x & 1) * 8 + (i & 7);
    gemm128x256_body<1, 0>(LDSb, by, bx, A, 1024, W, 1024, bias, Cb, 4096, 1024);
}

// ---------------------------------------------------------------- flash attention + entropy
// 512 threads: 8 waves cover 128 q-rows; one K/V stage serves all (halves fetch + staging).
__device__ __forceinline__ float red16sum(float v) {
    v += __shfl_xor(v, 1, 64);
    v += __shfl_xor(v, 2, 64);
    v += __shfl_xor(v, 4, 64);
    v += __shfl_xor(v, 8, 64);
    return v;
}

__global__ __launch_bounds__(512)
void attn_k(const bf16* __restrict__ Qp, const bf16* __restrict__ Kp,
            const bf16* __restrict__ Vt, bf16* __restrict__ ctx,
            float* __restrict__ entm) {
    __shared__ __attribute__((aligned(16))) bf16 Ks[64 * 64];
    __shared__ __attribute__((aligned(16))) bf16 Vs[64 * 64];
    __shared__ __attribute__((aligned(16))) bf16 Ps[8][16 * 72];
    const int t = threadIdx.x, w = t >> 6, l = t & 63;
    const int l15 = l & 15, lg = l >> 4;
    const int h = blockIdx.x, b = blockIdx.y, qt = blockIdx.z;
    const int qrow0 = b * LQ_ + qt * 128 + w * 16;

    bf16x8 aq[2];
#pragma unroll
    for (int kk = 0; kk < 2; ++kk)
        aq[kk] = *(const bf16x8*)(Qp + (size_t)(qrow0 + l15) * D_ + h * HD_ + kk * 32 + lg * 8);

    const int r = t >> 3, j = t & 7;
    const bf16* pK = Kp + (size_t)(b * LK_ + r) * 1024 + h * HD_ + ((j ^ (r & 7)) << 3);
    const bf16* pV = Vt + (size_t)(h * HD_ + r) * (size_t)MK_ + b * LK_ + ((j ^ (r & 7)) << 3);
    const int ldso = w * 512;   // wave-uniform; HW adds lane*16B

    auto STAGE = [&](int c) {
        GLOAD_LDS16(pK + (size_t)c * 64 * 1024, (bf16*)Ks + ldso);
        GLOAD_LDS16(pV + (size_t)c * 64,        (bf16*)Vs + ldso);
    };

    f32x4 o[4];
    float Zp[4], S1p[4];
#pragma unroll
    for (int n = 0; n < 4; ++n) o[n] = f32x4{0.f, 0.f, 0.f, 0.f};
#pragma unroll
    for (int r2 = 0; r2 < 4; ++r2) { Zp[r2] = 0.f; S1p[r2] = 0.f; }

    const float K1 = 0.125f * LOG2E_;
    const float K0 = -CSHIFT_ * LOG2E_;
    const int swk = l15 & 7;

    for (int c = 0; c < LK_ / 64; ++c) {
        STAGE(c);
        asm volatile("s_waitcnt vmcnt(0)" ::: "memory");
        __builtin_amdgcn_s_barrier();

        f32x4 s[4];
#pragma unroll
        for (int n = 0; n < 4; ++n) {
            s[n] = f32x4{0.f, 0.f, 0.f, 0.f};
#pragma unroll
            for (int kk = 0; kk < 2; ++kk) {
                bf16x8 bk = *(const bf16x8*)&Ks[(n * 16 + l15) * 64 + ((((kk << 2) | lg) ^ swk) << 3)];
                s[n] = __builtin_amdgcn_mfma_f32_16x16x32_bf16(aq[kk], bk, s[n], 0, 0, 0);
            }
        }

        float p[4][4];
#pragma unroll
        for (int r2 = 0; r2 < 4; ++r2) {
#pragma unroll
            for (int n = 0; n < 4; ++n) {
                float sv = s[n][r2];
                float pv = exp2f(fmaf(sv, K1, K0));
                p[n][r2] = pv;
                Zp[r2] += pv;
                S1p[r2] = fmaf(pv, sv, S1p[r2]);
            }
        }

#pragma unroll
        for (int r2 = 0; r2 < 4; ++r2)
#pragma unroll
            for (int n = 0; n < 4; ++n)
                Ps[w][(lg * 4 + r2) * 72 + ((n ^ lg) << 4) + l15] = (bf16)p[n][r2];

        bf16x8 ap[2];
#pragma unroll
        for (int kk = 0; kk < 2; ++kk)
            ap[kk] = *(const bf16x8*)&Ps[w][l15 * 72 + ((kk * 32 + lg * 8) ^ (((l15 >> 2) & 3) << 4))];
#pragma unroll
        for (int n = 0; n < 4; ++n)
#pragma unroll
            for (int kk = 0; kk < 2; ++kk) {
                bf16x8 bv = *(const bf16x8*)&Vs[(n * 16 + l15) * 64 + ((((kk << 2) | lg) ^ swk) << 3)];
                o[n] = __builtin_amdgcn_mfma_f32_16x16x32_bf16(ap[kk], bv, o[n], 0, 0, 0);
            }

        asm volatile("s_waitcnt lgkmcnt(0)" ::: "memory");
        __builtin_amdgcn_sched_barrier(0);
        __builtin_amdgcn_s_barrier();
    }

#pragma unroll
    for (int r2 = 0; r2 < 4; ++r2) {
        float Zr = red16sum(Zp[r2]);
        float S1r = red16sum(S1p[r2]) * 0.125f;
        float inv = 1.0f / Zr;
        int grow = qrow0 + lg * 4 + r2;
#pragma unroll
        for (int n = 0; n < 4; ++n)
            ctx[(size_t)grow * D_ + h * HD_ + n * 16 + l15] = (bf16)(o[n][r2] * inv);
        if (l15 == 0) {
            float ent = (CSHIFT_ + logf(Zr) - S1r * inv) * INV_LN_LK_ * (1.0f / 16.0f);
            atomicAdd(&entm[grow], ent);
        }
    }
}

// ---------------------------------------------------------------- block reductions
__device__ __forceinline__ float blk_sum(float v, float* sb) {
#pragma unroll
    for (int m = 1; m < 64; m <<= 1) v += __shfl_xor(v, m, 64);
    int w = threadIdx.x >> 6;
    __syncthreads();
    if ((threadIdx.x & 63) == 0) sb[w] = v;
    __syncthreads();
    return sb[0] + sb[1] + sb[2] + sb[3];
}
__device__ __forceinline__ float2 blk_sum2(float2 v, float* sb) {
#pragma unroll
    for (int m = 1; m < 64; m <<= 1) {
        v.x += __shfl_xor(v.x, m, 64);
        v.y += __shfl_xor(v.y, m, 64);
    }
    int w = threadIdx.x >> 6;
    __syncthreads();
    if ((threadIdx.x & 63) == 0) { sb[w * 2] = v.x; sb[w * 2 + 1] = v.y; }
    __syncthreads();
    return make_float2(sb[0] + sb[2] + sb[4] + sb[6], sb[1] + sb[3] + sb[5] + sb[7]);
}

// ---------------------------------------------------------------- gate + first LN (one row/block; q in bf16)
__global__ __launch_bounds__(256)
void gate_ln1_k(const bf16* __restrict__ xb,
                const bf16* __restrict__ gp0, const bf16* __restrict__ gp1,
                const float* __restrict__ gb1, const float* __restrict__ gw2,
                const float* __restrict__ gb2, const float* __restrict__ entm,
                const float* __restrict__ lng, const float* __restrict__ lnb,
                bf16* __restrict__ q2b) {
    __shared__ float sb[8];
    const int row = blockIdx.x, t = threadIdx.x, c0 = t * 4;
    bf16x4 pa = *(const bf16x4*)(gp0 + (size_t)row * D_ + c0);
    bf16x4 pb = *(const bf16x4*)(gp1 + (size_t)row * D_ + c0);
    float4 hb = *(const float4*)(gb1 + c0);
    float h0 = gelu_f((float)pa[0] + (float)pb[0] + hb.x);
    float h1 = gelu_f((float)pa[1] + (float)pb[1] + hb.y);
    float h2 = gelu_f((float)pa[2] + (float)pb[2] + hb.z);
    float h3 = gelu_f((float)pa[3] + (float)pb[3] + hb.w);
    float4 g4 = *(const float4*)(gw2 + c0);
    float dot = h0 * g4.x + h1 * g4.y + h2 * g4.z + h3 * g4.w;
    dot = blk_sum(dot, sb);
    float g = 1.0f / (1.0f + expf(-(dot + gb2[0])));
    float conf = fminf(fmaxf(1.0f - entm[row], 0.0f), 1.0f);
    g *= conf;
    bf16x4 qv = *(const bf16x4*)(xb + (size_t)row * 2048 + c0);
    bf16x4 a4 = *(const bf16x4*)(xb + (size_t)row * 2048 + 1024 + c0);
    float y[4] = { (float)qv[0] + (float)a4[0] * g, (float)qv[1] + (float)a4[1] * g,
                   (float)qv[2] + (float)a4[2] * g, (float)qv[3] + (float)a4[3] * g };
    float2 ss = blk_sum2(make_float2(y[0] + y[1] + y[2] + y[3],
                                     y[0]*y[0] + y[1]*y[1] + y[2]*y[2] + y[3]*y[3]), sb);
    float mu = ss.x * (1.0f / D_);
    float var = ss.y * (1.0f / D_) - mu * mu;
    float rs = rsqrtf(var + 1e-5f);
    float4 gg = *(const float4*)(lng + c0);
    float4 bb = *(const float4*)(lnb + c0);
    bf16x4 ob;
    ob[0] = (bf16)((y[0] - mu) * rs * gg.x + bb.x);
    ob[1] = (bf16)((y[1] - mu) * rs * gg.y + bb.y);
    ob[2] = (bf16)((y[2] - mu) * rs * gg.z + bb.z);
    ob[3] = (bf16)((y[3] - mu) * rs * gg.w + bb.w);
    *(bf16x4*)(q2b + (size_t)row * D_ + c0) = ob;
}

// ---------------------------------------------------------------- residual(bf16) + 4 ffn partials + LN -> out
__global__ __launch_bounds__(256)
void ln2_k(const bf16* __restrict__ q2b, const bf16* __restrict__ f0,
           const bf16* __restrict__ f1, const bf16* __restrict__ f2,
           const bf16* __restrict__ f3, const float* __restrict__ b2,
           const float* __restrict__ lng, const float* __restrict__ lnb,
           float* __restrict__ outp) {
    __shared__ float sb[8];
    const int row = blockIdx.x, t = threadIdx.x, c0 = t * 4;
    bf16x4 a4 = *(const bf16x4*)(q2b + (size_t)row * D_ + c0);
    bf16x4 p0 = *(const bf16x4*)(f0 + (size_t)row * D_ + c0);
    bf16x4 p1 = *(const bf16x4*)(f1 + (size_t)row * D_ + c0);
    bf16x4 p2 = *(const bf16x4*)(f2 + (size_t)row * D_ + c0);
    bf16x4 p3 = *(const bf16x4*)(f3 + (size_t)row * D_ + c0);
    float4 bv = *(const float4*)(b2 + c0);
    float y[4];
#pragma unroll
    for (int i = 0; i < 4; ++i)
        y[i] = (float)a4[i] + (float)p0[i] + (float)p1[i] + (float)p2[i] + (float)p3[i]
             + ((const float*)&bv)[i];
    float2 ss = blk_sum2(make_float2(y[0] + y[1] + y[2] + y[3],
                                     y[0]*y[0] + y[1]*y[1] + y[2]*y[2] + y[3]*y[3]), sb);
    float mu = ss.x * (1.0f / D_);
    float var = ss.y * (1.0f / D_) - mu * mu;
    float rs = rsqrtf(var + 1e-5f);
    float4 gg = *(const float4*)(lng + c0);
    float4 bb = *(const float4*)(lnb + c0);
    *(float4*)(outp + (size_t)row * D_ + c0) = make_float4(
        (y[0] - mu) * rs * gg.x + bb.x, (y[1] - mu) * rs * gg.y + bb.y,
        (y[2] - mu) * rs * gg.z + bb.z, (y[3] - mu) * rs * gg.w + bb.w);
}

// ---------------------------------------------------------------- launch
extern "C" void kernel_launch(void* const* d_in, const int* in_sizes, int n_in,
                              void* d_out, int out_size, void* d_ws, size_t ws_size,
                              hipStream_t stream) {
    (void)in_sizes; (void)n_in; (void)out_size; (void)ws_size;
    const float* q    = (const float*)d_in[0];
    const float* kv   = (const float*)d_in[2];
    const float* ipw  = (const float*)d_in[4];
    const float* ipb  = (const float*)d_in[5];
    const float* outw = (const float*)d_in[6];
    const float* outb = (const float*)d_in[7];
    const float* lng  = (const float*)d_in[8];
    const float* lnb  = (const float*)d_in[9];
    const float* w1   = (const float*)d_in[10];
    const float* b1   = (const float*)d_in[11];
    const float* w2   = (const float*)d_in[12];
    const float* b2   = (const float*)d_in[13];
    const float* gw1  = (const float*)d_in[14];
    const float* gb1  = (const float*)d_in[15];
    const float* gw2  = (const float*)d_in[16];
    const float* gb2  = (const float*)d_in[17];

    char* ws = (char*)d_ws;
    const size_t MB = 1u << 20;
    bf16*  ipw_b  = (bf16*)(ws + 0);         // [0,6)
    bf16*  outw_b = (bf16*)(ws + 6 * MB);    // [6,8)
    bf16*  w1_b   = (bf16*)(ws + 8 * MB);    // [8,16)
    bf16*  w2_b   = (bf16*)(ws + 16 * MB);   // [16,24)
    bf16*  gw1_b  = (bf16*)(ws + 24 * MB);   // [24,28)
    bf16*  x_b    = (bf16*)(ws + 28 * MB);   // [28,44)  4096x2048 [q | attn_out]
    bf16*  kv_b   = (bf16*)(ws + 44 * MB);   // [44,60)
    bf16*  Qp     = (bf16*)(ws + 60 * MB);   // [60,68)
    bf16*  Kp     = (bf16*)(ws + 68 * MB);   // [68,84)  [8192][1024]
    bf16*  Vt     = (bf16*)(ws + 84 * MB);   // [84,100) [1024][8192] = V^T
    bf16*  ctx    = (bf16*)(ws + 100 * MB);  // [100,108)
    // reuse (lifetimes disjoint, stream-ordered):
    bf16*  gp0    = (bf16*)(ws + 44 * MB);   // [44,52)  over kv_b (dead after proj3)
    bf16*  gp1    = (bf16*)(ws + 52 * MB);   // [52,60)
    bf16*  q2b    = (bf16*)(ws + 100 * MB);  // [100,108) over ctx (dead after opq)
    bf16*  h1     = (bf16*)(ws + 44 * MB);   // [44,76)  over gp0/gp1/Qp (dead after gate_ln1/attn)
    bf16*  fp0    = (bf16*)(ws + 28 * MB);   // [28,36)  over x_b (dead after gate_ln1)
    bf16*  fp1    = (bf16*)(ws + 36 * MB);   // [36,44)
    bf16*  fp2    = (bf16*)(ws + 0);         // [0,8)    over ipw_b (dead)
    bf16*  fp3    = (bf16*)(ws + 8 * MB);    // [8,16)   over w1_b (dead after ffn1)

    float* out  = (float*)d_out;
    float* entm = out + (size_t)MQ_ * D_;

    (void)hipMemsetAsync(entm, 0, (size_t)MQ_ * sizeof(float), stream);

    cast_all_k<<<13312, 256, 0, stream>>>(ipw, outw, w1, w2, gw1, q, kv,
                                          ipw_b, outw_b, w1_b, w2_b, gw1_b, x_b, kv_b);

    gemm_proj3_k<<<640, 512, 0, stream>>>(x_b, kv_b, ipw_b, ipb, Qp, Kp, Vt);
    attn_k<<<dim3(H_, B_, LQ_ / 128), 512, 0, stream>>>(Qp, Kp, Vt, ctx, entm);
    gemm_opq_k<<<512, 256, 0, stream>>>(ctx, outw_b, outb, x_b, gw1_b, x_b + 1024, gp0);
    gemm_gatek_k<<<256, 256, 0, stream>>>(x_b, gw1_b, gp1);
    gate_ln1_k<<<MQ_, 256, 0, stream>>>(x_b, gp0, gp1, gb1, gw2, gb2, entm, lng, lnb, q2b);
    gemmA_ffn1_k<<<dim3(16, 32), 512, 0, stream>>>(q2b, w1_b, b1, h1);
    gemm_ffn2_k<<<1024, 256, 0, stream>>>(h1, w2_b, fp0, fp1, fp2, fp3);
    ln2_k<<<MQ_, 256, 0, stream>>>(q2b, fp0, fp1, fp2, fp3, b2, lng, lnb, out);
}